// Round 6
// baseline (1377.559 us; speedup 1.0000x reference)
//
#include <hip/hip_runtime.h>
#include <stdint.h>

#define DIM    680
#define DPAD   768      // 3 x 256 tiles
#define NB_Q   24
#define SPLITS 72
#define STAGES 12       // 864 g-chunks / SPLITS
#define NTILE  6        // upper-triangle 256x256 tiles of 3x3

typedef __bf16 bf16x8 __attribute__((ext_vector_type(8)));
typedef __bf16 bf16x2 __attribute__((ext_vector_type(2)));
typedef float  f32x16 __attribute__((ext_vector_type(16)));

typedef __attribute__((address_space(3))) unsigned       lds_u32;
typedef __attribute__((address_space(1))) const unsigned glb_u32;

__constant__ int c_tj[NTILE] = {0, 0, 0, 1, 1, 2};
__constant__ int c_ti[NTILE] = {0, 1, 2, 1, 2, 2};

static __device__ __forceinline__ unsigned f2bf(float x) {
    union { float f; unsigned u; } c; c.f = x;
    unsigned u = c.u;
    return (u + 0x7FFFu + ((u >> 16) & 1u)) >> 16;  // RNE
}

// HW packed convert: compiler emits v_cvt_pk_bf16_f32 (RNE) for paired casts.
static __device__ __forceinline__ unsigned pk2(float lo, float hi) {
    bf16x2 v = {(__bf16)lo, (__bf16)hi};
    return __builtin_bit_cast(unsigned, v);
}

static __device__ __forceinline__ float bf2f(unsigned short h) {
    union { unsigned u; float f; } c; c.u = ((unsigned)h) << 16;
    return c.f;
}

// ---------------------------------------------------------------------------
// k12-v2 (fused k1+k2): parts[split][tile] = sum over the split's 12 chunks
//     of A_band(tj)^T * A_band(ti), A = D * sqrt(qw[beta(g)]) in bf16,
//     computed on the fly from fp32 D (no awt intermediate).
//
//     v2 vs v1 (R5 counters: 123us, HBM 13%, Mfma 14%, VALU 34%, Occ 16.6%
//     -> latency-bound at 1 block/CU):
//      (a) SPLITS 36 -> 72: 432 blocks => ~2 blocks/CU so one block's MFMA
//          overlaps the other's conv/load phase. __launch_bounds__(512,4)
//          pins VGPR<=128 to guarantee 4 waves/SIMD residency (LDS 64.5KB
//          x2 = 129 <= 160KB fits).
//      (b) conv uses HW v_cvt_pk_bf16_f32 (paired __bf16 casts) instead of
//          4-op manual RNE: conv VALU roughly halves (VALU was the top
//          busy counter).
//
//     Structure per stage: conv st (auto-vmcnt waits on regs) -> issue
//     st+1 loads (fly across ds_writes+barrier+MFMA) -> lgkmcnt(0) +
//     s_barrier -> MFMA gather (XOR-swizzled slots) -> lgkmcnt(0) +
//     s_barrier.  Raw barriers only: __syncthreads would drain vmcnt(0)
//     and kill the prefetch.
// ---------------------------------------------------------------------------
__global__ __launch_bounds__(512, 4) void k12_gram(
        const float* __restrict__ D, const float* __restrict__ qw,
        uint2* __restrict__ parts) {
    __shared__ float sq[NB_Q];
    __shared__ uint4 smA[2048];   // 256 cols x 8 slots (swizzled), 32 KB
    __shared__ uint4 smB[2048];
    const int t  = threadIdx.x;
    const int h       = blockIdx.x;              // 0..431
    const int logical = (h & 7) * 54 + (h >> 3); // bijective (432 = 8*54)
    const int split   = logical / 6;
    const int t6      = logical % 6;
    const int tj    = c_tj[t6];   // row band of M
    const int ti    = c_ti[t6];   // col band of M
    const bool diag = (tj == ti);
    // staging mapping
    const int cl_ = t & 255;      // column within band
    const int hg  = t >> 8;       // kc half: kc = hg*4 + 0..3
    const int cA  = tj * 256 + cl_;
    const int cB  = ti * 256 + cl_;
    const bool vA = (cA < DIM);
    const bool vB = (cB < DIM);
    const int cAc = vA ? cA : (DIM - 1);   // clamp: uniform VMEM counts
    const int cBc = vB ? cB : (DIM - 1);
    // MFMA mapping
    const int wave  = t >> 6;
    const int lane  = t & 63;
    const int wm    = wave & 3;   // m: 64-row band
    const int wn    = wave >> 2;  // n: 128-col band
    const int cl    = lane & 31;
    const int half  = lane >> 5;

    f32x16 acc[2][4];
    const f32x16 zero = {};
#pragma unroll
    for (int a = 0; a < 2; ++a)
#pragma unroll
        for (int b = 0; b < 4; ++b) acc[a][b] = zero;

    float ra[32], rb[32];   // staged fp32 (static indexing only)

#define K12_LOAD(reg_, st_, csrc_)                                            \
    do {                                                                      \
        const int g0_ = (split * STAGES + (st_)) * 64 + hg * 32;              \
        _Pragma("unroll")                                                     \
        for (int u_ = 0; u_ < 32; ++u_)                                       \
            reg_[u_] = D[(size_t)(g0_ + u_) * DIM + (csrc_)];                 \
    } while (0)

#define K12_CONV(reg_, valid_, sm_, st_)                                      \
    do {                                                                      \
        const int gg_ = (split * STAGES + (st_)) * 64 + hg * 32;              \
        _Pragma("unroll")                                                     \
        for (int kcg_ = 0; kcg_ < 4; ++kcg_) {                                \
            const int G_ = gg_ + kcg_ * 8;                                    \
            const int q_ = G_ / 48;                                           \
            const int r_ = G_ - q_ * 48;                                      \
            const float s0_ = sq[q_ % 24];                                    \
            const float s1_ = sq[(q_ + 1) % 24];                              \
            float e_[8];                                                      \
            _Pragma("unroll")                                                 \
            for (int j_ = 0; j_ < 8; ++j_) {                                  \
                const float sc_ = (r_ + j_ < 48) ? s0_ : s1_;                 \
                e_[j_] = (valid_) ? reg_[kcg_ * 8 + j_] * sc_ : 0.f;          \
            }                                                                 \
            uint4 o_;                                                         \
            o_.x = pk2(e_[0], e_[1]);                                         \
            o_.y = pk2(e_[2], e_[3]);                                         \
            o_.z = pk2(e_[4], e_[5]);                                         \
            o_.w = pk2(e_[6], e_[7]);                                         \
            sm_[cl_ * 8 + ((hg * 4 + kcg_) ^ (cl_ & 7))] = o_;                \
        }                                                                     \
    } while (0)

    // prologue: stage-0 loads fly while sq is set up
    K12_LOAD(ra, 0, cAc);
    if (!diag) K12_LOAD(rb, 0, cBc);
    if (t < NB_Q) sq[t] = sqrtf(qw[t]);
    asm volatile("s_waitcnt lgkmcnt(0)" ::: "memory");
    __builtin_amdgcn_s_barrier();   // sq visible (vmcnt untouched)

    for (int st = 0; st < STAGES; ++st) {
        // convert st (compiler emits the precise vmcnt wait for ra/rb here),
        // then immediately issue st+1's loads: they fly across the ds_writes,
        // barrier, and the whole MFMA phase.
        K12_CONV(ra, vA, smA, st);
        if (st + 1 < STAGES) K12_LOAD(ra, st + 1, cAc);
        if (!diag) {
            K12_CONV(rb, vB, smB, st);
            if (st + 1 < STAGES) K12_LOAD(rb, st + 1, cBc);
        }
        asm volatile("s_waitcnt lgkmcnt(0)" ::: "memory");  // my ds_writes done
        __builtin_amdgcn_s_barrier();   // tiles complete for all waves

        const bf16x8* pA = reinterpret_cast<const bf16x8*>(smA);
        const bf16x8* pB = diag ? pA : reinterpret_cast<const bf16x8*>(smB);
#pragma unroll
        for (int t4 = 0; t4 < 4; ++t4) {          // K = 64 per stage, 16/mfma
            const int kc = 2 * t4 + half;
            bf16x8 af[2], bfr[4];
#pragma unroll
            for (int ms = 0; ms < 2; ++ms) {
                const int col = wm * 64 + ms * 32 + cl;
                af[ms] = pA[col * 8 + (kc ^ (col & 7))];
            }
#pragma unroll
            for (int ns = 0; ns < 4; ++ns) {
                const int col = wn * 128 + ns * 32 + cl;
                bfr[ns] = pB[col * 8 + (kc ^ (col & 7))];
            }
            __builtin_amdgcn_s_setprio(1);
#pragma unroll
            for (int ms = 0; ms < 2; ++ms)
#pragma unroll
                for (int ns = 0; ns < 4; ++ns)
                    acc[ms][ns] = __builtin_amdgcn_mfma_f32_32x32x16_bf16(
                        af[ms], bfr[ns], acc[ms][ns], 0, 0, 0);
            __builtin_amdgcn_s_setprio(0);
        }
        asm volatile("s_waitcnt lgkmcnt(0)" ::: "memory");  // my frag reads done
        __builtin_amdgcn_s_barrier();   // all reads done -> tiles reusable
    }
#undef K12_LOAD
#undef K12_CONV

    // row-quad packed bf16 stores: full-line coalesced, no atomics
    uint2* pt = parts + (size_t)(split * NTILE + t6) * 16384;
#pragma unroll
    for (int ms = 0; ms < 2; ++ms) {
        const int rowb = wm * 64 + ms * 32 + 4 * half;   // multiple of 4
#pragma unroll
        for (int ns = 0; ns < 4; ++ns) {
            const int colt = wn * 128 + ns * 32 + cl;
#pragma unroll
            for (int q = 0; q < 4; ++q) {                // rows rowb+8q .. +3
                uint2 w;
                w.x = f2bf(acc[ms][ns][q * 4 + 0]) | (f2bf(acc[ms][ns][q * 4 + 1]) << 16);
                w.y = f2bf(acc[ms][ns][q * 4 + 2]) | (f2bf(acc[ms][ns][q * 4 + 3]) << 16);
                pt[(size_t)(((rowb >> 2) + 2 * q) * 256 + colt)] = w;
            }
        }
    }
}

// ---------------------------------------------------------------------------
// kF: F (1024 x 680 fp32) -> Fb bf16 (1024 x 768, k-padded with zeros),
//     row-major. 768%8==0 and 680%8==0 -> clean uint4 (8 bf16) packing.
// ---------------------------------------------------------------------------
__global__ __launch_bounds__(256) void kf_conv(const float* __restrict__ F,
                                               uint4* __restrict__ Fb) {
    const int idx = blockIdx.x * 256 + threadIdx.x;   // 98304 uint4's
    const int row = idx / 96;                         // 768/8 = 96 per row
    const int c0  = (idx % 96) * 8;
    uint4 o = {0u, 0u, 0u, 0u};
    if (c0 < DIM) {
        const float4 a = *reinterpret_cast<const float4*>(F + (size_t)row * DIM + c0);
        const float4 b = *reinterpret_cast<const float4*>(F + (size_t)row * DIM + c0 + 4);
        o.x = f2bf(a.x) | (f2bf(a.y) << 16);
        o.y = f2bf(a.z) | (f2bf(a.w) << 16);
        o.z = f2bf(b.x) | (f2bf(b.y) << 16);
        o.w = f2bf(b.z) | (f2bf(b.w) << 16);
    }
    Fb[idx] = o;
}

// ---------------------------------------------------------------------------
// k2r: Mb[768x768 bf16] = sum over 72 split-partials per tile, + mirror.
//     Writes bf16 directly in k3's operand format (M symmetric ->
//     row-major Mb serves as both M and M^T).
// ---------------------------------------------------------------------------
__global__ __launch_bounds__(256) void k2_reduce(
        const uint2* __restrict__ parts, unsigned short* __restrict__ Mb) {
    const int t6 = blockIdx.y;
    const int tj = c_tj[t6];
    const int ti = c_ti[t6];
    const int idx4 = blockIdx.x * 256 + threadIdx.x;   // uint4 index, 8192/tile
    const int w0 = idx4 * 2;
    const int quad = w0 >> 8;
    const int c = w0 & 255;                            // even
    float s[8] = {0.f, 0.f, 0.f, 0.f, 0.f, 0.f, 0.f, 0.f};
    const uint4* base = reinterpret_cast<const uint4*>(parts) + idx4;
#pragma unroll 8
    for (int sp = 0; sp < SPLITS; ++sp) {
        const uint4 u = base[(size_t)(sp * NTILE + t6) * 8192];
        s[0] += bf2f((unsigned short)(u.x & 0xFFFF));
        s[1] += bf2f((unsigned short)(u.x >> 16));
        s[2] += bf2f((unsigned short)(u.y & 0xFFFF));
        s[3] += bf2f((unsigned short)(u.y >> 16));
        s[4] += bf2f((unsigned short)(u.z & 0xFFFF));
        s[5] += bf2f((unsigned short)(u.z >> 16));
        s[6] += bf2f((unsigned short)(u.w & 0xFFFF));
        s[7] += bf2f((unsigned short)(u.w >> 16));
    }
    const int R = tj * 256 + 4 * quad;
    const int C = ti * 256 + c;
#pragma unroll
    for (int i = 0; i < 4; ++i) {      // rows R..R+3, cols C,C+1
        const unsigned w = f2bf(s[i]) | (f2bf(s[4 + i]) << 16);
        *reinterpret_cast<unsigned*>(Mb + (size_t)(R + i) * DPAD + C) = w;
    }
    if (ti != tj) {                    // mirror: rows C,C+1, cols R..R+3
        uint2 m0, m1;
        m0.x = f2bf(s[0]) | (f2bf(s[1]) << 16);
        m0.y = f2bf(s[2]) | (f2bf(s[3]) << 16);
        m1.x = f2bf(s[4]) | (f2bf(s[5]) << 16);
        m1.y = f2bf(s[6]) | (f2bf(s[7]) << 16);
        *reinterpret_cast<uint2*>(Mb + (size_t)(C + 0) * DPAD + R) = m0;
        *reinterpret_cast<uint2*>(Mb + (size_t)(C + 1) * DPAD + R) = m1;
    }
}

// ---------------------------------------------------------------------------
// k3: out(1024 x 680) = F @ M via bf16 MFMA, full K=768. Operands Fb/Mb are
//     bf16 row-major with rows = contiguous K runs (M symmetric).
//     1 wave / block, 64x64 tile, grid (16, 11); operands L2/L3-resident.
//     global_load_lds with source-side XOR pre-swizzle, double-buffered
//     with counted vmcnt(16).
// ---------------------------------------------------------------------------
__global__ __launch_bounds__(64) void k3_mfma(const uint4* __restrict__ Fb,
                                              const uint4* __restrict__ Mb,
                                              float* __restrict__ out) {
    __shared__ uint4 sA[2][512];   // 64 cols x 8 k-chunks, swizzled, 2x8 KB
    __shared__ uint4 sB[2][512];
    const int t    = threadIdx.x;   // 0..63
    const int n0   = blockIdx.x * 64;
    const int i0   = blockIdx.y * 64;
    const int cl   = t & 31;
    const int half = t >> 5;

    f32x16 acc[2][2];
    const f32x16 zero = {};
    acc[0][0] = zero; acc[0][1] = zero; acc[1][0] = zero; acc[1][1] = zero;

#define K3_STAGE(ck_, buf_)                                                   \
    do {                                                                      \
        const int kcs_ = t & 7;                                               \
        _Pragma("unroll")                                                     \
        for (int j = 0; j < 8; ++j) {                                         \
            const int nl_ = j * 8 + (t >> 3);                                 \
            const int sc_ = (ck_) * 8 + (kcs_ ^ (nl_ & 7));                   \
            __builtin_amdgcn_global_load_lds(                                 \
                (glb_u32*)(Fb + (size_t)(n0 + nl_) * 96 + sc_),               \
                (lds_u32*)(&sA[(buf_)][j * 64 + t]), 16, 0, 0);               \
            __builtin_amdgcn_global_load_lds(                                 \
                (glb_u32*)(Mb + (size_t)(i0 + nl_) * 96 + sc_),               \
                (lds_u32*)(&sB[(buf_)][j * 64 + t]), 16, 0, 0);               \
        }                                                                     \
    } while (0)

    K3_STAGE(0, 0);
    asm volatile("s_waitcnt vmcnt(0)" ::: "memory");

    for (int ck = 0; ck < 12; ++ck) {          // K = 768 = 12 x 64
        const int cur = ck & 1;
        if (ck + 1 < 12) {
            asm volatile("s_waitcnt lgkmcnt(0)" ::: "memory");
            K3_STAGE(ck + 1, cur ^ 1);
            asm volatile("s_waitcnt vmcnt(16)" ::: "memory");  // cur's 16 done
        }
        const bf16x8* pA = reinterpret_cast<const bf16x8*>(sA[cur]);
        const bf16x8* pB = reinterpret_cast<const bf16x8*>(sB[cur]);
#pragma unroll
        for (int t4 = 0; t4 < 4; ++t4) {
            const int kc = 2 * t4 + half;
            bf16x8 af[2], bv[2];
#pragma unroll
            for (int ms = 0; ms < 2; ++ms) {
                const int col = ms * 32 + cl;
                af[ms] = pA[col * 8 + (kc ^ (col & 7))];
            }
#pragma unroll
            for (int ns = 0; ns < 2; ++ns) {
                const int col = ns * 32 + cl;
                bv[ns] = pB[col * 8 + (kc ^ (col & 7))];
            }
#pragma unroll
            for (int ms = 0; ms < 2; ++ms)
#pragma unroll
                for (int ns = 0; ns < 2; ++ns)
                    acc[ms][ns] = __builtin_amdgcn_mfma_f32_32x32x16_bf16(
                        af[ms], bv[ns], acc[ms][ns], 0, 0, 0);
        }
    }
#undef K3_STAGE

    // C layout (32x32): col = lane&31, row = (reg&3) + 8*(reg>>2) + 4*half
#pragma unroll
    for (int ms = 0; ms < 2; ++ms) {
        const int rowb = ms * 32 + 4 * half;
#pragma unroll
        for (int ns = 0; ns < 2; ++ns) {
            const int col = i0 + ns * 32 + cl;
            if (col < DIM) {
#pragma unroll
                for (int q = 0; q < 4; ++q)
#pragma unroll
                    for (int j = 0; j < 4; ++j)
                        out[(size_t)(n0 + rowb + 8 * q + j) * DIM + col]
                            = acc[ms][ns][4 * q + j];
            }
        }
    }
}

extern "C" void kernel_launch(void* const* d_in, const int* in_sizes, int n_in,
                              void* d_out, int out_size, void* d_ws, size_t ws_size,
                              hipStream_t stream) {
    const float* F  = (const float*)d_in[0];   // (1024, 680)
    const float* D  = (const float*)d_in[1];   // (48, 24, 48, 680)
    const float* qw = (const float*)d_in[2];   // (24,)
    float* out = (float*)d_out;
    char*  ws  = (char*)d_ws;

    uint2* parts = (uint2*)ws;                                  // 54.0 MiB bf16
    const size_t parts_bytes = (size_t)SPLITS * NTILE * 16384 * 8;  // 56,623,104
    unsigned short* Mb = (unsigned short*)(ws + parts_bytes);   // 1.125 MiB
    const size_t mb_bytes = (size_t)DPAD * DPAD * 2;            // 1,179,648
    uint4* Fb = (uint4*)(ws + parts_bytes + mb_bytes);          // 1.5 MiB

    k12_gram<<<dim3(SPLITS * NTILE), 512, 0, stream>>>(D, qw, parts);
    kf_conv<<<dim3(1024 * DPAD / 8 / 256), 256, 0, stream>>>(F, Fb);
    k2_reduce<<<dim3(32, NTILE), 256, 0, stream>>>(parts, Mb);
    k3_mfma<<<dim3(16, 11), 64, 0, stream>>>(Fb, (const uint4*)Mb, out);
}

// Round 7
// 304.151 us; speedup vs baseline: 4.5292x; 4.5292x over previous
//
#include <hip/hip_runtime.h>
#include <stdint.h>

#define DIM    680
#define DPAD   768      // 3 x 256 tiles
#define NB_Q   24
#define SPLITS 72
#define STAGES 12       // 864 g-chunks / SPLITS
#define NTILE  6        // upper-triangle 256x256 tiles of 3x3

typedef __bf16 bf16x8 __attribute__((ext_vector_type(8)));
typedef __bf16 bf16x2 __attribute__((ext_vector_type(2)));
typedef float  f32x16 __attribute__((ext_vector_type(16)));

typedef __attribute__((address_space(3))) unsigned       lds_u32;
typedef __attribute__((address_space(1))) const unsigned glb_u32;

__constant__ int c_tj[NTILE] = {0, 0, 0, 1, 1, 2};
__constant__ int c_ti[NTILE] = {0, 1, 2, 1, 2, 2};

static __device__ __forceinline__ unsigned f2bf(float x) {
    union { float f; unsigned u; } c; c.f = x;
    unsigned u = c.u;
    return (u + 0x7FFFu + ((u >> 16) & 1u)) >> 16;  // RNE
}

// HW packed convert: compiler emits v_cvt_pk_bf16_f32 (RNE) for paired casts.
static __device__ __forceinline__ unsigned pk2(float lo, float hi) {
    bf16x2 v = {(__bf16)lo, (__bf16)hi};
    return __builtin_bit_cast(unsigned, v);
}

static __device__ __forceinline__ float bf2f(unsigned short h) {
    union { unsigned u; float f; } c; c.u = ((unsigned)h) << 16;
    return c.f;
}

// ---------------------------------------------------------------------------
// k12-v3 (fused k1+k2): parts[split][tile] = sum over the split's 12 chunks
//     of A_band(tj)^T * A_band(ti), A = D * sqrt(qw[beta(g)]) in bf16,
//     computed on the fly from fp32 D (no awt intermediate).
//
//     v3 vs v2 (R6 post-mortem): __launch_bounds__(512,4) forced the
//     allocator to a ~64-VGPR budget; the kernel needs ~124 (acc = 128
//     f32 lanes + 64 staging regs) -> total spill, +2.4 GB scratch
//     traffic, 10x regression.  REVERTED to natural allocation: VGPR=124
//     already fits 4 waves/SIMD (496 <= 512) and LDS 129 <= 160 KB, so
//     2 blocks/CU is achievable without any bound.  SPLITS=72 (432
//     blocks) stays: that was the piece R5 was missing (216 blocks < 256
//     CUs capped occupancy at 1 block/CU by grid size alone).
//
//     Structure per stage: conv st (auto-vmcnt waits on regs) -> issue
//     st+1 loads (fly across ds_writes+barrier+MFMA) -> lgkmcnt(0) +
//     s_barrier -> MFMA gather (XOR-swizzled slots) -> lgkmcnt(0) +
//     s_barrier.  Raw barriers only: __syncthreads would drain vmcnt(0)
//     and kill the prefetch.
// ---------------------------------------------------------------------------
__global__ __launch_bounds__(512) void k12_gram(
        const float* __restrict__ D, const float* __restrict__ qw,
        uint2* __restrict__ parts) {
    __shared__ float sq[NB_Q];
    __shared__ uint4 smA[2048];   // 256 cols x 8 slots (swizzled), 32 KB
    __shared__ uint4 smB[2048];
    const int t  = threadIdx.x;
    const int h       = blockIdx.x;              // 0..431
    const int logical = (h & 7) * 54 + (h >> 3); // bijective (432 = 8*54)
    const int split   = logical / 6;
    const int t6      = logical % 6;
    const int tj    = c_tj[t6];   // row band of M
    const int ti    = c_ti[t6];   // col band of M
    const bool diag = (tj == ti);
    // staging mapping
    const int cl_ = t & 255;      // column within band
    const int hg  = t >> 8;       // kc half: kc = hg*4 + 0..3
    const int cA  = tj * 256 + cl_;
    const int cB  = ti * 256 + cl_;
    const bool vA = (cA < DIM);
    const bool vB = (cB < DIM);
    const int cAc = vA ? cA : (DIM - 1);   // clamp: uniform VMEM counts
    const int cBc = vB ? cB : (DIM - 1);
    // MFMA mapping
    const int wave  = t >> 6;
    const int lane  = t & 63;
    const int wm    = wave & 3;   // m: 64-row band
    const int wn    = wave >> 2;  // n: 128-col band
    const int cl    = lane & 31;
    const int half  = lane >> 5;

    f32x16 acc[2][4];
    const f32x16 zero = {};
#pragma unroll
    for (int a = 0; a < 2; ++a)
#pragma unroll
        for (int b = 0; b < 4; ++b) acc[a][b] = zero;

    float ra[32], rb[32];   // staged fp32 (static indexing only)

#define K12_LOAD(reg_, st_, csrc_)                                            \
    do {                                                                      \
        const int g0_ = (split * STAGES + (st_)) * 64 + hg * 32;              \
        _Pragma("unroll")                                                     \
        for (int u_ = 0; u_ < 32; ++u_)                                       \
            reg_[u_] = D[(size_t)(g0_ + u_) * DIM + (csrc_)];                 \
    } while (0)

#define K12_CONV(reg_, valid_, sm_, st_)                                      \
    do {                                                                      \
        const int gg_ = (split * STAGES + (st_)) * 64 + hg * 32;              \
        _Pragma("unroll")                                                     \
        for (int kcg_ = 0; kcg_ < 4; ++kcg_) {                                \
            const int G_ = gg_ + kcg_ * 8;                                    \
            const int q_ = G_ / 48;                                           \
            const int r_ = G_ - q_ * 48;                                      \
            const float s0_ = sq[q_ % 24];                                    \
            const float s1_ = sq[(q_ + 1) % 24];                              \
            float e_[8];                                                      \
            _Pragma("unroll")                                                 \
            for (int j_ = 0; j_ < 8; ++j_) {                                  \
                const float sc_ = (r_ + j_ < 48) ? s0_ : s1_;                 \
                e_[j_] = (valid_) ? reg_[kcg_ * 8 + j_] * sc_ : 0.f;          \
            }                                                                 \
            uint4 o_;                                                         \
            o_.x = pk2(e_[0], e_[1]);                                         \
            o_.y = pk2(e_[2], e_[3]);                                         \
            o_.z = pk2(e_[4], e_[5]);                                         \
            o_.w = pk2(e_[6], e_[7]);                                         \
            sm_[cl_ * 8 + ((hg * 4 + kcg_) ^ (cl_ & 7))] = o_;                \
        }                                                                     \
    } while (0)

    // prologue: stage-0 loads fly while sq is set up
    K12_LOAD(ra, 0, cAc);
    if (!diag) K12_LOAD(rb, 0, cBc);
    if (t < NB_Q) sq[t] = sqrtf(qw[t]);
    asm volatile("s_waitcnt lgkmcnt(0)" ::: "memory");
    __builtin_amdgcn_s_barrier();   // sq visible (vmcnt untouched)

    for (int st = 0; st < STAGES; ++st) {
        // convert st (compiler emits the precise vmcnt wait for ra/rb here),
        // then immediately issue st+1's loads: they fly across the ds_writes,
        // barrier, and the whole MFMA phase.
        K12_CONV(ra, vA, smA, st);
        if (st + 1 < STAGES) K12_LOAD(ra, st + 1, cAc);
        if (!diag) {
            K12_CONV(rb, vB, smB, st);
            if (st + 1 < STAGES) K12_LOAD(rb, st + 1, cBc);
        }
        asm volatile("s_waitcnt lgkmcnt(0)" ::: "memory");  // my ds_writes done
        __builtin_amdgcn_s_barrier();   // tiles complete for all waves

        const bf16x8* pA = reinterpret_cast<const bf16x8*>(smA);
        const bf16x8* pB = diag ? pA : reinterpret_cast<const bf16x8*>(smB);
#pragma unroll
        for (int t4 = 0; t4 < 4; ++t4) {          // K = 64 per stage, 16/mfma
            const int kc = 2 * t4 + half;
            bf16x8 af[2], bfr[4];
#pragma unroll
            for (int ms = 0; ms < 2; ++ms) {
                const int col = wm * 64 + ms * 32 + cl;
                af[ms] = pA[col * 8 + (kc ^ (col & 7))];
            }
#pragma unroll
            for (int ns = 0; ns < 4; ++ns) {
                const int col = wn * 128 + ns * 32 + cl;
                bfr[ns] = pB[col * 8 + (kc ^ (col & 7))];
            }
            __builtin_amdgcn_s_setprio(1);
#pragma unroll
            for (int ms = 0; ms < 2; ++ms)
#pragma unroll
                for (int ns = 0; ns < 4; ++ns)
                    acc[ms][ns] = __builtin_amdgcn_mfma_f32_32x32x16_bf16(
                        af[ms], bfr[ns], acc[ms][ns], 0, 0, 0);
            __builtin_amdgcn_s_setprio(0);
        }
        asm volatile("s_waitcnt lgkmcnt(0)" ::: "memory");  // my frag reads done
        __builtin_amdgcn_s_barrier();   // all reads done -> tiles reusable
    }
#undef K12_LOAD
#undef K12_CONV

    // row-quad packed bf16 stores: full-line coalesced, no atomics
    uint2* pt = parts + (size_t)(split * NTILE + t6) * 16384;
#pragma unroll
    for (int ms = 0; ms < 2; ++ms) {
        const int rowb = wm * 64 + ms * 32 + 4 * half;   // multiple of 4
#pragma unroll
        for (int ns = 0; ns < 4; ++ns) {
            const int colt = wn * 128 + ns * 32 + cl;
#pragma unroll
            for (int q = 0; q < 4; ++q) {                // rows rowb+8q .. +3
                uint2 w;
                w.x = f2bf(acc[ms][ns][q * 4 + 0]) | (f2bf(acc[ms][ns][q * 4 + 1]) << 16);
                w.y = f2bf(acc[ms][ns][q * 4 + 2]) | (f2bf(acc[ms][ns][q * 4 + 3]) << 16);
                pt[(size_t)(((rowb >> 2) + 2 * q) * 256 + colt)] = w;
            }
        }
    }
}

// ---------------------------------------------------------------------------
// kF: F (1024 x 680 fp32) -> Fb bf16 (1024 x 768, k-padded with zeros),
//     row-major. 768%8==0 and 680%8==0 -> clean uint4 (8 bf16) packing.
// ---------------------------------------------------------------------------
__global__ __launch_bounds__(256) void kf_conv(const float* __restrict__ F,
                                               uint4* __restrict__ Fb) {
    const int idx = blockIdx.x * 256 + threadIdx.x;   // 98304 uint4's
    const int row = idx / 96;                         // 768/8 = 96 per row
    const int c0  = (idx % 96) * 8;
    uint4 o = {0u, 0u, 0u, 0u};
    if (c0 < DIM) {
        const float4 a = *reinterpret_cast<const float4*>(F + (size_t)row * DIM + c0);
        const float4 b = *reinterpret_cast<const float4*>(F + (size_t)row * DIM + c0 + 4);
        o.x = f2bf(a.x) | (f2bf(a.y) << 16);
        o.y = f2bf(a.z) | (f2bf(a.w) << 16);
        o.z = f2bf(b.x) | (f2bf(b.y) << 16);
        o.w = f2bf(b.z) | (f2bf(b.w) << 16);
    }
    Fb[idx] = o;
}

// ---------------------------------------------------------------------------
// k2r: Mb[768x768 bf16] = sum over 72 split-partials per tile, + mirror.
//     Writes bf16 directly in k3's operand format (M symmetric ->
//     row-major Mb serves as both M and M^T).
// ---------------------------------------------------------------------------
__global__ __launch_bounds__(256) void k2_reduce(
        const uint2* __restrict__ parts, unsigned short* __restrict__ Mb) {
    const int t6 = blockIdx.y;
    const int tj = c_tj[t6];
    const int ti = c_ti[t6];
    const int idx4 = blockIdx.x * 256 + threadIdx.x;   // uint4 index, 8192/tile
    const int w0 = idx4 * 2;
    const int quad = w0 >> 8;
    const int c = w0 & 255;                            // even
    float s[8] = {0.f, 0.f, 0.f, 0.f, 0.f, 0.f, 0.f, 0.f};
    const uint4* base = reinterpret_cast<const uint4*>(parts) + idx4;
#pragma unroll 8
    for (int sp = 0; sp < SPLITS; ++sp) {
        const uint4 u = base[(size_t)(sp * NTILE + t6) * 8192];
        s[0] += bf2f((unsigned short)(u.x & 0xFFFF));
        s[1] += bf2f((unsigned short)(u.x >> 16));
        s[2] += bf2f((unsigned short)(u.y & 0xFFFF));
        s[3] += bf2f((unsigned short)(u.y >> 16));
        s[4] += bf2f((unsigned short)(u.z & 0xFFFF));
        s[5] += bf2f((unsigned short)(u.z >> 16));
        s[6] += bf2f((unsigned short)(u.w & 0xFFFF));
        s[7] += bf2f((unsigned short)(u.w >> 16));
    }
    const int R = tj * 256 + 4 * quad;
    const int C = ti * 256 + c;
#pragma unroll
    for (int i = 0; i < 4; ++i) {      // rows R..R+3, cols C,C+1
        const unsigned w = f2bf(s[i]) | (f2bf(s[4 + i]) << 16);
        *reinterpret_cast<unsigned*>(Mb + (size_t)(R + i) * DPAD + C) = w;
    }
    if (ti != tj) {                    // mirror: rows C,C+1, cols R..R+3
        uint2 m0, m1;
        m0.x = f2bf(s[0]) | (f2bf(s[1]) << 16);
        m0.y = f2bf(s[2]) | (f2bf(s[3]) << 16);
        m1.x = f2bf(s[4]) | (f2bf(s[5]) << 16);
        m1.y = f2bf(s[6]) | (f2bf(s[7]) << 16);
        *reinterpret_cast<uint2*>(Mb + (size_t)(C + 0) * DPAD + R) = m0;
        *reinterpret_cast<uint2*>(Mb + (size_t)(C + 1) * DPAD + R) = m1;
    }
}

// ---------------------------------------------------------------------------
// k3: out(1024 x 680) = F @ M via bf16 MFMA, full K=768. Operands Fb/Mb are
//     bf16 row-major with rows = contiguous K runs (M symmetric).
//     1 wave / block, 64x64 tile, grid (16, 11); operands L2/L3-resident.
//     global_load_lds with source-side XOR pre-swizzle, double-buffered
//     with counted vmcnt(16).
// ---------------------------------------------------------------------------
__global__ __launch_bounds__(64) void k3_mfma(const uint4* __restrict__ Fb,
                                              const uint4* __restrict__ Mb,
                                              float* __restrict__ out) {
    __shared__ uint4 sA[2][512];   // 64 cols x 8 k-chunks, swizzled, 2x8 KB
    __shared__ uint4 sB[2][512];
    const int t    = threadIdx.x;   // 0..63
    const int n0   = blockIdx.x * 64;
    const int i0   = blockIdx.y * 64;
    const int cl   = t & 31;
    const int half = t >> 5;

    f32x16 acc[2][2];
    const f32x16 zero = {};
    acc[0][0] = zero; acc[0][1] = zero; acc[1][0] = zero; acc[1][1] = zero;

#define K3_STAGE(ck_, buf_)                                                   \
    do {                                                                      \
        const int kcs_ = t & 7;                                               \
        _Pragma("unroll")                                                     \
        for (int j = 0; j < 8; ++j) {                                         \
            const int nl_ = j * 8 + (t >> 3);                                 \
            const int sc_ = (ck_) * 8 + (kcs_ ^ (nl_ & 7));                   \
            __builtin_amdgcn_global_load_lds(                                 \
                (glb_u32*)(Fb + (size_t)(n0 + nl_) * 96 + sc_),               \
                (lds_u32*)(&sA[(buf_)][j * 64 + t]), 16, 0, 0);               \
            __builtin_amdgcn_global_load_lds(                                 \
                (glb_u32*)(Mb + (size_t)(i0 + nl_) * 96 + sc_),               \
                (lds_u32*)(&sB[(buf_)][j * 64 + t]), 16, 0, 0);               \
        }                                                                     \
    } while (0)

    K3_STAGE(0, 0);
    asm volatile("s_waitcnt vmcnt(0)" ::: "memory");

    for (int ck = 0; ck < 12; ++ck) {          // K = 768 = 12 x 64
        const int cur = ck & 1;
        if (ck + 1 < 12) {
            asm volatile("s_waitcnt lgkmcnt(0)" ::: "memory");
            K3_STAGE(ck + 1, cur ^ 1);
            asm volatile("s_waitcnt vmcnt(16)" ::: "memory");  // cur's 16 done
        }
        const bf16x8* pA = reinterpret_cast<const bf16x8*>(sA[cur]);
        const bf16x8* pB = reinterpret_cast<const bf16x8*>(sB[cur]);
#pragma unroll
        for (int t4 = 0; t4 < 4; ++t4) {
            const int kc = 2 * t4 + half;
            bf16x8 af[2], bv[2];
#pragma unroll
            for (int ms = 0; ms < 2; ++ms) {
                const int col = ms * 32 + cl;
                af[ms] = pA[col * 8 + (kc ^ (col & 7))];
            }
#pragma unroll
            for (int ns = 0; ns < 2; ++ns) {
                const int col = ns * 32 + cl;
                bv[ns] = pB[col * 8 + (kc ^ (col & 7))];
            }
#pragma unroll
            for (int ms = 0; ms < 2; ++ms)
#pragma unroll
                for (int ns = 0; ns < 2; ++ns)
                    acc[ms][ns] = __builtin_amdgcn_mfma_f32_32x32x16_bf16(
                        af[ms], bv[ns], acc[ms][ns], 0, 0, 0);
        }
    }
#undef K3_STAGE

    // C layout (32x32): col = lane&31, row = (reg&3) + 8*(reg>>2) + 4*half
#pragma unroll
    for (int ms = 0; ms < 2; ++ms) {
        const int rowb = ms * 32 + 4 * half;
#pragma unroll
        for (int ns = 0; ns < 2; ++ns) {
            const int col = i0 + ns * 32 + cl;
            if (col < DIM) {
#pragma unroll
                for (int q = 0; q < 4; ++q)
#pragma unroll
                    for (int j = 0; j < 4; ++j)
                        out[(size_t)(n0 + rowb + 8 * q + j) * DIM + col]
                            = acc[ms][ns][4 * q + j];
            }
        }
    }
}

extern "C" void kernel_launch(void* const* d_in, const int* in_sizes, int n_in,
                              void* d_out, int out_size, void* d_ws, size_t ws_size,
                              hipStream_t stream) {
    const float* F  = (const float*)d_in[0];   // (1024, 680)
    const float* D  = (const float*)d_in[1];   // (48, 24, 48, 680)
    const float* qw = (const float*)d_in[2];   // (24,)
    float* out = (float*)d_out;
    char*  ws  = (char*)d_ws;

    uint2* parts = (uint2*)ws;                                  // 54.0 MiB bf16
    const size_t parts_bytes = (size_t)SPLITS * NTILE * 16384 * 8;  // 56,623,104
    unsigned short* Mb = (unsigned short*)(ws + parts_bytes);   // 1.125 MiB
    const size_t mb_bytes = (size_t)DPAD * DPAD * 2;            // 1,179,648
    uint4* Fb = (uint4*)(ws + parts_bytes + mb_bytes);          // 1.5 MiB

    k12_gram<<<dim3(SPLITS * NTILE), 512, 0, stream>>>(D, qw, parts);
    kf_conv<<<dim3(1024 * DPAD / 8 / 256), 256, 0, stream>>>(F, Fb);
    k2_reduce<<<dim3(32, NTILE), 256, 0, stream>>>(parts, Mb);
    k3_mfma<<<dim3(16, 11), 64, 0, stream>>>(Fb, (const uint4*)Mb, out);
}

// Round 8
// 277.315 us; speedup vs baseline: 4.9675x; 1.0968x over previous
//
#include <hip/hip_runtime.h>
#include <stdint.h>

#define DIM    680
#define DPAD   768      // 3 x 256 tiles
#define NB_Q   24
#define SPLITS 72
#define STAGES 12       // 864 g-chunks / SPLITS
#define NTILE  6        // upper-triangle 256x256 tiles of 3x3

typedef __bf16 bf16x8 __attribute__((ext_vector_type(8)));
typedef __bf16 bf16x2 __attribute__((ext_vector_type(2)));
typedef float  f32x16 __attribute__((ext_vector_type(16)));
typedef float  f32x4  __attribute__((ext_vector_type(4)));

typedef __attribute__((address_space(3))) unsigned       lds_u32;
typedef __attribute__((address_space(1))) const unsigned glb_u32;

__constant__ int c_tj[NTILE] = {0, 0, 0, 1, 1, 2};
__constant__ int c_ti[NTILE] = {0, 1, 2, 1, 2, 2};

static __device__ __forceinline__ unsigned f2bf(float x) {
    union { float f; unsigned u; } c; c.f = x;
    unsigned u = c.u;
    return (u + 0x7FFFu + ((u >> 16) & 1u)) >> 16;  // RNE
}

// HW packed convert: compiler emits v_cvt_pk_bf16_f32 (RNE) for paired casts.
static __device__ __forceinline__ unsigned pk2(float lo, float hi) {
    bf16x2 v = {(__bf16)lo, (__bf16)hi};
    return __builtin_bit_cast(unsigned, v);
}

static __device__ __forceinline__ float bf2f(unsigned short h) {
    union { unsigned u; float f; } c; c.u = ((unsigned)h) << 16;
    return c.f;
}

// ---------------------------------------------------------------------------
// k12-v4 (fused k1+k2): parts[split][tile] = sum over the split's 12 chunks
//     of A_band(tj)^T * A_band(ti), A = D * sqrt(qw[beta(g)]) in bf16,
//     computed on the fly from fp32 D.
//
//     v4 vs v3 (R7 post-mortem): occupancy is HARD-CAPPED at 1 block/CU by
//     registers (arch 124 + acc 128 in AGPR = 252/wave -> 2 waves/SIMD);
//     the 2-blocks/CU theory is structurally dead.  The 9k stall cyc/stage
//     must fall to ILP within the wave:
//      (a) kc-major LDS layout [kc][col] (slot = kc*256+col): frag reads =
//          contiguous half-wave segments; conv ds_writes = 64B-contiguous
//          per thread (2-way = free).  Old layout's writes were ~32-way
//          conflicted (SQ_LDS_BANK_CONFLICT 3.98M).  No swizzle needed.
//      (b) ONE barrier per stage: double-buffered bf16 tiles (128 KB LDS,
//          free at 1 block/CU); conv(st+1)->buf^1 runs in the SAME region
//          as MFMA(st) from buf -> compiler co-schedules VALU with MFMA
//          (separate pipes).  v3 was phase-serial (Mfma 14%, VALU 31%).
//      (c) dwordx4 staging: thread owns 8 rows x 4 cols per band; VMEM
//          instrs/stage/wave 64 -> 16, addr VALU ~1/4.  Loads issued 2
//          stages ahead, flying across raw s_barriers (lgkm-only waits).
// ---------------------------------------------------------------------------
__global__ __launch_bounds__(512) void k12_gram(
        const float* __restrict__ D, const float* __restrict__ qw,
        uint2* __restrict__ parts) {
    __shared__ float sq[NB_Q];
    __shared__ uint4 smA[2][2048];   // [kc][col] kc-major, 2 x 32 KB
    __shared__ uint4 smB[2][2048];
    const int t  = threadIdx.x;
    const int h       = blockIdx.x;              // 0..431
    const int logical = (h & 7) * 54 + (h >> 3); // bijective (432 = 8*54)
    const int split   = logical / 6;
    const int t6      = logical % 6;
    const int tj    = c_tj[t6];   // row band of M
    const int ti    = c_ti[t6];   // col band of M
    const bool diag = (tj == ti);
    // staging: thread owns rows rg*8..+7 (= k-chunk kc=rg) x cols c0..c0+3
    const int rg = t >> 6;        // 0..7, wave-uniform
    const int c0 = 4 * (t & 63);  // 0..252; lane-contiguous float4 => coalesced
    const int cA = tj * 256 + c0;
    const int cB = ti * 256 + c0;
    const bool vA = (cA < DIM);   // 680%4==0: whole float4 valid or not
    const bool vB = (cB < DIM);
    const int cAc = vA ? cA : (DIM - 4);   // clamp: uniform VMEM counts
    const int cBc = vB ? cB : (DIM - 4);
    // MFMA mapping
    const int wave  = t >> 6;
    const int lane  = t & 63;
    const int wm    = wave & 3;   // m: 64-row band
    const int wn    = wave >> 2;  // n: 128-col band
    const int cl    = lane & 31;
    const int half  = lane >> 5;

    f32x16 acc[2][4];
    const f32x16 zero = {};
#pragma unroll
    for (int a = 0; a < 2; ++a)
#pragma unroll
        for (int b = 0; b < 4; ++b) acc[a][b] = zero;

    f32x4 fa[8], fb[8];   // staged rows (static indexing only)

#define K12_LOAD(reg_, st_, csrc_)                                            \
    do {                                                                      \
        const int g0_ = (split * STAGES + (st_)) * 64 + rg * 8;               \
        _Pragma("unroll")                                                     \
        for (int j_ = 0; j_ < 8; ++j_)                                        \
            reg_[j_] = *reinterpret_cast<const f32x4*>(                       \
                D + (size_t)(g0_ + j_) * DIM + (csrc_));                      \
    } while (0)

#define K12_CONV(reg_, valid_, smx_, st_)                                     \
    do {                                                                      \
        const int G_ = (split * STAGES + (st_)) * 64 + rg * 8;                \
        const int q_ = G_ / 48;                                               \
        const int r_ = G_ - q_ * 48;                                          \
        const float s0_ = sq[q_ % 24];                                        \
        const float s1_ = sq[(q_ + 1) % 24];                                  \
        float sc_[8];                                                         \
        _Pragma("unroll")                                                     \
        for (int j_ = 0; j_ < 8; ++j_) sc_[j_] = (r_ + j_ < 48) ? s0_ : s1_;  \
        _Pragma("unroll")                                                     \
        for (int jc_ = 0; jc_ < 4; ++jc_) {                                   \
            float e_[8];                                                      \
            _Pragma("unroll")                                                 \
            for (int j_ = 0; j_ < 8; ++j_)                                    \
                e_[j_] = (valid_) ? reg_[j_][jc_] * sc_[j_] : 0.f;            \
            uint4 o_;                                                         \
            o_.x = pk2(e_[0], e_[1]);                                         \
            o_.y = pk2(e_[2], e_[3]);                                         \
            o_.z = pk2(e_[4], e_[5]);                                         \
            o_.w = pk2(e_[6], e_[7]);                                         \
            smx_[rg * 256 + c0 + jc_] = o_;   /* slot = kc*256 + col */       \
        }                                                                     \
    } while (0)

    // prologue: stage-0 loads fly while sq is set up
    K12_LOAD(fa, 0, cAc);
    if (!diag) K12_LOAD(fb, 0, cBc);
    if (t < NB_Q) sq[t] = sqrtf(qw[t]);
    asm volatile("s_waitcnt lgkmcnt(0)" ::: "memory");
    __builtin_amdgcn_s_barrier();   // sq visible (vmcnt untouched)
    K12_CONV(fa, vA, smA[0], 0);    // auto-vmcnt waits on fa here
    if (!diag) K12_CONV(fb, vB, smB[0], 0);
    K12_LOAD(fa, 1, cAc);           // st1 loads fly across barrier + stage 0
    if (!diag) K12_LOAD(fb, 1, cBc);
    asm volatile("s_waitcnt lgkmcnt(0)" ::: "memory");
    __builtin_amdgcn_s_barrier();   // buf0 complete for all waves

    for (int st = 0; st < STAGES; ++st) {
        const int cur = st & 1;
        // conv(st+1) into the other buffer + issue st+2 loads; co-scheduled
        // with MFMA(st) below (separate VALU/MFMA pipes, no barrier between).
        if (st + 1 < STAGES) {
            K12_CONV(fa, vA, smA[cur ^ 1], st + 1);
            if (st + 2 < STAGES) K12_LOAD(fa, st + 2, cAc);
            if (!diag) {
                K12_CONV(fb, vB, smB[cur ^ 1], st + 1);
                if (st + 2 < STAGES) K12_LOAD(fb, st + 2, cBc);
            }
        }

        const bf16x8* pA = reinterpret_cast<const bf16x8*>(smA[cur]);
        const bf16x8* pB = diag ? pA : reinterpret_cast<const bf16x8*>(smB[cur]);
#pragma unroll
        for (int t4 = 0; t4 < 4; ++t4) {          // K = 64 per stage, 16/mfma
            const int kc = 2 * t4 + half;
            bf16x8 af[2], bfr[4];
#pragma unroll
            for (int ms = 0; ms < 2; ++ms) {
                const int col = wm * 64 + ms * 32 + cl;
                af[ms] = pA[kc * 256 + col];
            }
#pragma unroll
            for (int ns = 0; ns < 4; ++ns) {
                const int col = wn * 128 + ns * 32 + cl;
                bfr[ns] = pB[kc * 256 + col];
            }
            __builtin_amdgcn_s_setprio(1);
#pragma unroll
            for (int ms = 0; ms < 2; ++ms)
#pragma unroll
                for (int ns = 0; ns < 4; ++ns)
                    acc[ms][ns] = __builtin_amdgcn_mfma_f32_32x32x16_bf16(
                        af[ms], bfr[ns], acc[ms][ns], 0, 0, 0);
            __builtin_amdgcn_s_setprio(0);
        }
        asm volatile("s_waitcnt lgkmcnt(0)" ::: "memory");  // my ds ops done
        __builtin_amdgcn_s_barrier();   // writes(st+1) + reads(st) retired
    }
#undef K12_LOAD
#undef K12_CONV

    // row-quad packed bf16 stores: full-line coalesced, no atomics
    uint2* pt = parts + (size_t)(split * NTILE + t6) * 16384;
#pragma unroll
    for (int ms = 0; ms < 2; ++ms) {
        const int rowb = wm * 64 + ms * 32 + 4 * half;   // multiple of 4
#pragma unroll
        for (int ns = 0; ns < 4; ++ns) {
            const int colt = wn * 128 + ns * 32 + cl;
#pragma unroll
            for (int q = 0; q < 4; ++q) {                // rows rowb+8q .. +3
                uint2 w;
                w.x = f2bf(acc[ms][ns][q * 4 + 0]) | (f2bf(acc[ms][ns][q * 4 + 1]) << 16);
                w.y = f2bf(acc[ms][ns][q * 4 + 2]) | (f2bf(acc[ms][ns][q * 4 + 3]) << 16);
                pt[(size_t)(((rowb >> 2) + 2 * q) * 256 + colt)] = w;
            }
        }
    }
}

// ---------------------------------------------------------------------------
// kF: F (1024 x 680 fp32) -> Fb bf16 (1024 x 768, k-padded with zeros),
//     row-major. 768%8==0 and 680%8==0 -> clean uint4 (8 bf16) packing.
// ---------------------------------------------------------------------------
__global__ __launch_bounds__(256) void kf_conv(const float* __restrict__ F,
                                               uint4* __restrict__ Fb) {
    const int idx = blockIdx.x * 256 + threadIdx.x;   // 98304 uint4's
    const int row = idx / 96;                         // 768/8 = 96 per row
    const int c0  = (idx % 96) * 8;
    uint4 o = {0u, 0u, 0u, 0u};
    if (c0 < DIM) {
        const float4 a = *reinterpret_cast<const float4*>(F + (size_t)row * DIM + c0);
        const float4 b = *reinterpret_cast<const float4*>(F + (size_t)row * DIM + c0 + 4);
        o.x = f2bf(a.x) | (f2bf(a.y) << 16);
        o.y = f2bf(a.z) | (f2bf(a.w) << 16);
        o.z = f2bf(b.x) | (f2bf(b.y) << 16);
        o.w = f2bf(b.z) | (f2bf(b.w) << 16);
    }
    Fb[idx] = o;
}

// ---------------------------------------------------------------------------
// k2r: Mb[768x768 bf16] = sum over 72 split-partials per tile, + mirror.
//     Writes bf16 directly in k3's operand format (M symmetric ->
//     row-major Mb serves as both M and M^T).
// ---------------------------------------------------------------------------
__global__ __launch_bounds__(256) void k2_reduce(
        const uint2* __restrict__ parts, unsigned short* __restrict__ Mb) {
    const int t6 = blockIdx.y;
    const int tj = c_tj[t6];
    const int ti = c_ti[t6];
    const int idx4 = blockIdx.x * 256 + threadIdx.x;   // uint4 index, 8192/tile
    const int w0 = idx4 * 2;
    const int quad = w0 >> 8;
    const int c = w0 & 255;                            // even
    float s[8] = {0.f, 0.f, 0.f, 0.f, 0.f, 0.f, 0.f, 0.f};
    const uint4* base = reinterpret_cast<const uint4*>(parts) + idx4;
#pragma unroll 8
    for (int sp = 0; sp < SPLITS; ++sp) {
        const uint4 u = base[(size_t)(sp * NTILE + t6) * 8192];
        s[0] += bf2f((unsigned short)(u.x & 0xFFFF));
        s[1] += bf2f((unsigned short)(u.x >> 16));
        s[2] += bf2f((unsigned short)(u.y & 0xFFFF));
        s[3] += bf2f((unsigned short)(u.y >> 16));
        s[4] += bf2f((unsigned short)(u.z & 0xFFFF));
        s[5] += bf2f((unsigned short)(u.z >> 16));
        s[6] += bf2f((unsigned short)(u.w & 0xFFFF));
        s[7] += bf2f((unsigned short)(u.w >> 16));
    }
    const int R = tj * 256 + 4 * quad;
    const int C = ti * 256 + c;
#pragma unroll
    for (int i = 0; i < 4; ++i) {      // rows R..R+3, cols C,C+1
        const unsigned w = f2bf(s[i]) | (f2bf(s[4 + i]) << 16);
        *reinterpret_cast<unsigned*>(Mb + (size_t)(R + i) * DPAD + C) = w;
    }
    if (ti != tj) {                    // mirror: rows C,C+1, cols R..R+3
        uint2 m0, m1;
        m0.x = f2bf(s[0]) | (f2bf(s[1]) << 16);
        m0.y = f2bf(s[2]) | (f2bf(s[3]) << 16);
        m1.x = f2bf(s[4]) | (f2bf(s[5]) << 16);
        m1.y = f2bf(s[6]) | (f2bf(s[7]) << 16);
        *reinterpret_cast<uint2*>(Mb + (size_t)(C + 0) * DPAD + R) = m0;
        *reinterpret_cast<uint2*>(Mb + (size_t)(C + 1) * DPAD + R) = m1;
    }
}

// ---------------------------------------------------------------------------
// k3: out(1024 x 680) = F @ M via bf16 MFMA, full K=768. Operands Fb/Mb are
//     bf16 row-major with rows = contiguous K runs (M symmetric).
//     1 wave / block, 64x64 tile, grid (16, 11); operands L2/L3-resident.
//     global_load_lds with source-side XOR pre-swizzle, double-buffered
//     with counted vmcnt(16).
// ---------------------------------------------------------------------------
__global__ __launch_bounds__(64) void k3_mfma(const uint4* __restrict__ Fb,
                                              const uint4* __restrict__ Mb,
                                              float* __restrict__ out) {
    __shared__ uint4 sA[2][512];   // 64 cols x 8 k-chunks, swizzled, 2x8 KB
    __shared__ uint4 sB[2][512];
    const int t    = threadIdx.x;   // 0..63
    const int n0   = blockIdx.x * 64;
    const int i0   = blockIdx.y * 64;
    const int cl   = t & 31;
    const int half = t >> 5;

    f32x16 acc[2][2];
    const f32x16 zero = {};
    acc[0][0] = zero; acc[0][1] = zero; acc[1][0] = zero; acc[1][1] = zero;

#define K3_STAGE(ck_, buf_)                                                   \
    do {                                                                      \
        const int kcs_ = t & 7;                                               \
        _Pragma("unroll")                                                     \
        for (int j = 0; j < 8; ++j) {                                         \
            const int nl_ = j * 8 + (t >> 3);                                 \
            const int sc_ = (ck_) * 8 + (kcs_ ^ (nl_ & 7));                   \
            __builtin_amdgcn_global_load_lds(                                 \
                (glb_u32*)(Fb + (size_t)(n0 + nl_) * 96 + sc_),               \
                (lds_u32*)(&sA[(buf_)][j * 64 + t]), 16, 0, 0);               \
            __builtin_amdgcn_global_load_lds(                                 \
                (glb_u32*)(Mb + (size_t)(i0 + nl_) * 96 + sc_),               \
                (lds_u32*)(&sB[(buf_)][j * 64 + t]), 16, 0, 0);               \
        }                                                                     \
    } while (0)

    K3_STAGE(0, 0);
    asm volatile("s_waitcnt vmcnt(0)" ::: "memory");

    for (int ck = 0; ck < 12; ++ck) {          // K = 768 = 12 x 64
        const int cur = ck & 1;
        if (ck + 1 < 12) {
            asm volatile("s_waitcnt lgkmcnt(0)" ::: "memory");
            K3_STAGE(ck + 1, cur ^ 1);
            asm volatile("s_waitcnt vmcnt(16)" ::: "memory");  // cur's 16 done
        }
        const bf16x8* pA = reinterpret_cast<const bf16x8*>(sA[cur]);
        const bf16x8* pB = reinterpret_cast<const bf16x8*>(sB[cur]);
#pragma unroll
        for (int t4 = 0; t4 < 4; ++t4) {
            const int kc = 2 * t4 + half;
            bf16x8 af[2], bv[2];
#pragma unroll
            for (int ms = 0; ms < 2; ++ms) {
                const int col = ms * 32 + cl;
                af[ms] = pA[col * 8 + (kc ^ (col & 7))];
            }
#pragma unroll
            for (int ns = 0; ns < 2; ++ns) {
                const int col = ns * 32 + cl;
                bv[ns] = pB[col * 8 + (kc ^ (col & 7))];
            }
#pragma unroll
            for (int ms = 0; ms < 2; ++ms)
#pragma unroll
                for (int ns = 0; ns < 2; ++ns)
                    acc[ms][ns] = __builtin_amdgcn_mfma_f32_32x32x16_bf16(
                        af[ms], bv[ns], acc[ms][ns], 0, 0, 0);
        }
    }
#undef K3_STAGE

    // C layout (32x32): col = lane&31, row = (reg&3) + 8*(reg>>2) + 4*half
#pragma unroll
    for (int ms = 0; ms < 2; ++ms) {
        const int rowb = ms * 32 + 4 * half;
#pragma unroll
        for (int ns = 0; ns < 2; ++ns) {
            const int col = i0 + ns * 32 + cl;
            if (col < DIM) {
#pragma unroll
                for (int q = 0; q < 4; ++q)
#pragma unroll
                    for (int j = 0; j < 4; ++j)
                        out[(size_t)(n0 + rowb + 8 * q + j) * DIM + col]
                            = acc[ms][ns][4 * q + j];
            }
        }
    }
}

extern "C" void kernel_launch(void* const* d_in, const int* in_sizes, int n_in,
                              void* d_out, int out_size, void* d_ws, size_t ws_size,
                              hipStream_t stream) {
    const float* F  = (const float*)d_in[0];   // (1024, 680)
    const float* D  = (const float*)d_in[1];   // (48, 24, 48, 680)
    const float* qw = (const float*)d_in[2];   // (24,)
    float* out = (float*)d_out;
    char*  ws  = (char*)d_ws;

    uint2* parts = (uint2*)ws;                                  // 54.0 MiB bf16
    const size_t parts_bytes = (size_t)SPLITS * NTILE * 16384 * 8;  // 56,623,104
    unsigned short* Mb = (unsigned short*)(ws + parts_bytes);   // 1.125 MiB
    const size_t mb_bytes = (size_t)DPAD * DPAD * 2;            // 1,179,648
    uint4* Fb = (uint4*)(ws + parts_bytes + mb_bytes);          // 1.5 MiB

    k12_gram<<<dim3(SPLITS * NTILE), 512, 0, stream>>>(D, qw, parts);
    kf_conv<<<dim3(1024 * DPAD / 8 / 256), 256, 0, stream>>>(F, Fb);
    k2_reduce<<<dim3(32, NTILE), 256, 0, stream>>>(parts, Mb);
    k3_mfma<<<dim3(16, 11), 64, 0, stream>>>(Fb, (const uint4*)Mb, out);
}

// Round 9
// 255.107 us; speedup vs baseline: 5.3999x; 1.0871x over previous
//
#include <hip/hip_runtime.h>
#include <stdint.h>

#define DIM    680
#define DPAD   768      // 3 x 256 tiles
#define NB_Q   24
#define SPLITS 36
#define STAGES 24       // 864 g-chunks / SPLITS
#define NTILE  6        // upper-triangle 256x256 tiles of 3x3

typedef __bf16 bf16x8 __attribute__((ext_vector_type(8)));
typedef __bf16 bf16x2 __attribute__((ext_vector_type(2)));
typedef float  f32x16 __attribute__((ext_vector_type(16)));
typedef float  f32x4  __attribute__((ext_vector_type(4)));

typedef __attribute__((address_space(3))) unsigned       lds_u32;
typedef __attribute__((address_space(1))) const unsigned glb_u32;

__constant__ int c_tj[NTILE] = {0, 0, 0, 1, 1, 2};
__constant__ int c_ti[NTILE] = {0, 1, 2, 1, 2, 2};

static __device__ __forceinline__ unsigned f2bf(float x) {
    union { float f; unsigned u; } c; c.f = x;
    unsigned u = c.u;
    return (u + 0x7FFFu + ((u >> 16) & 1u)) >> 16;  // RNE
}

// HW packed convert: compiler emits v_cvt_pk_bf16_f32 (RNE) for paired casts.
static __device__ __forceinline__ unsigned pk2(float lo, float hi) {
    bf16x2 v = {(__bf16)lo, (__bf16)hi};
    return __builtin_bit_cast(unsigned, v);
}

static __device__ __forceinline__ float bf2f(unsigned short h) {
    union { unsigned u; float f; } c; c.u = ((unsigned)h) << 16;
    return c.f;
}

// LDS bank swizzle for the [kc][col] tile: spreads conv's stride-64B lane
// writes across all 8 bank-groups; bijective within each aligned 8-col block
// so frag reads (contiguous 32-col spans) stay conflict-free.
static __device__ __forceinline__ int swz(int col) {
    return col ^ ((col >> 2) & 7);
}

// ---------------------------------------------------------------------------
// k12-v5 (fused k1+k2): parts[split][tile] = sum over the split's 24 chunks
//     of A_band(tj)^T * A_band(ti), A = D * sqrt(qw[beta(g)]) in bf16,
//     computed on the fly from fp32 D.
//
//     v5 vs v4 (R8 post-mortem: 91.5us, conflicts UP 5.97M, Mfma 19%):
//      (a) MFMA(st) FIRST, conv(st+1) AFTER.  v4's conv-first order chained
//          [vmcnt wait -> conv -> ds_writes -> frag ds_reads -> MFMA] fully
//          serial per wave (DS queue is in-order and the compiler cannot
//          prove buf[cur]/buf[cur^1] disjoint).  MFMA-first lets frag reads
//          issue right off the barrier and overlaps conv's vmcnt stall with
//          the other wave's MFMA phase.
//      (b) XOR bank swizzle col^((col>>2)&7) on conv writes + frag reads.
//          v4's write pattern (lane byte-stride 64) was ~32-way conflicted:
//          bank = (16*lane+4*jc)%32 -> all even lanes on one 4-bank set.
//          Swizzled: 8 consecutive lanes cover all 8 bank-groups (free);
//          reads permute within aligned 8-blocks (still free).
//      (c) SPLITS 36 (216 blocks x 24 stages): one clean round instead of
//          1.69, parts traffic halved (57 -> 28 MB).
// ---------------------------------------------------------------------------
__global__ __launch_bounds__(512) void k12_gram(
        const float* __restrict__ D, const float* __restrict__ qw,
        uint2* __restrict__ parts) {
    __shared__ float sq[NB_Q];
    __shared__ uint4 smA[2][2048];   // [kc][col] kc-major, swizzled, 2 x 32 KB
    __shared__ uint4 smB[2][2048];
    const int t  = threadIdx.x;
    const int h       = blockIdx.x;              // 0..215
    const int logical = (h & 7) * 27 + (h >> 3); // bijective (216 = 8*27)
    const int split   = logical / 6;
    const int t6      = logical % 6;
    const int tj    = c_tj[t6];   // row band of M
    const int ti    = c_ti[t6];   // col band of M
    const bool diag = (tj == ti);
    // staging: thread owns rows rg*8..+7 (= k-chunk kc=rg) x cols c0..c0+3
    const int rg = t >> 6;        // 0..7, wave-uniform
    const int c0 = 4 * (t & 63);  // 0..252; lane-contiguous float4 => coalesced
    const int cA = tj * 256 + c0;
    const int cB = ti * 256 + c0;
    const bool vA = (cA < DIM);   // 680%4==0: whole float4 valid or not
    const bool vB = (cB < DIM);
    const int cAc = vA ? cA : (DIM - 4);   // clamp: uniform VMEM counts
    const int cBc = vB ? cB : (DIM - 4);
    // MFMA mapping
    const int wave  = t >> 6;
    const int lane  = t & 63;
    const int wm    = wave & 3;   // m: 64-row band
    const int wn    = wave >> 2;  // n: 128-col band
    const int cl    = lane & 31;
    const int half  = lane >> 5;

    f32x16 acc[2][4];
    const f32x16 zero = {};
#pragma unroll
    for (int a = 0; a < 2; ++a)
#pragma unroll
        for (int b = 0; b < 4; ++b) acc[a][b] = zero;

    f32x4 fa[8], fb[8];   // staged rows (static indexing only)

#define K12_LOAD(reg_, st_, csrc_)                                            \
    do {                                                                      \
        const int g0_ = (split * STAGES + (st_)) * 64 + rg * 8;               \
        _Pragma("unroll")                                                     \
        for (int j_ = 0; j_ < 8; ++j_)                                        \
            reg_[j_] = *reinterpret_cast<const f32x4*>(                       \
                D + (size_t)(g0_ + j_) * DIM + (csrc_));                      \
    } while (0)

#define K12_CONV(reg_, valid_, smx_, st_)                                     \
    do {                                                                      \
        const int G_ = (split * STAGES + (st_)) * 64 + rg * 8;                \
        const int q_ = G_ / 48;                                               \
        const int r_ = G_ - q_ * 48;                                          \
        const float s0_ = sq[q_ % 24];                                        \
        const float s1_ = sq[(q_ + 1) % 24];                                  \
        float sc_[8];                                                         \
        _Pragma("unroll")                                                     \
        for (int j_ = 0; j_ < 8; ++j_) sc_[j_] = (r_ + j_ < 48) ? s0_ : s1_;  \
        _Pragma("unroll")                                                     \
        for (int jc_ = 0; jc_ < 4; ++jc_) {                                   \
            float e_[8];                                                      \
            _Pragma("unroll")                                                 \
            for (int j_ = 0; j_ < 8; ++j_)                                    \
                e_[j_] = (valid_) ? reg_[j_][jc_] * sc_[j_] : 0.f;            \
            uint4 o_;                                                         \
            o_.x = pk2(e_[0], e_[1]);                                         \
            o_.y = pk2(e_[2], e_[3]);                                         \
            o_.z = pk2(e_[4], e_[5]);                                         \
            o_.w = pk2(e_[6], e_[7]);                                         \
            smx_[rg * 256 + swz(c0 + jc_)] = o_;   /* slot = kc*256 + swz */  \
        }                                                                     \
    } while (0)

    // prologue: stage-0 loads fly while sq is set up
    K12_LOAD(fa, 0, cAc);
    if (!diag) K12_LOAD(fb, 0, cBc);
    if (t < NB_Q) sq[t] = sqrtf(qw[t]);
    asm volatile("s_waitcnt lgkmcnt(0)" ::: "memory");
    __builtin_amdgcn_s_barrier();   // sq visible (vmcnt untouched)
    K12_CONV(fa, vA, smA[0], 0);    // auto-vmcnt waits on fa here
    if (!diag) K12_CONV(fb, vB, smB[0], 0);
    K12_LOAD(fa, 1, cAc);           // st1 loads fly across barrier + stage 0
    if (!diag) K12_LOAD(fb, 1, cBc);
    asm volatile("s_waitcnt lgkmcnt(0)" ::: "memory");
    __builtin_amdgcn_s_barrier();   // buf0 complete for all waves

    for (int st = 0; st < STAGES; ++st) {
        const int cur = st & 1;

        // ---- MFMA(st) first: frag reads issue right off the barrier ----
        const bf16x8* pA = reinterpret_cast<const bf16x8*>(smA[cur]);
        const bf16x8* pB = diag ? pA : reinterpret_cast<const bf16x8*>(smB[cur]);
#pragma unroll
        for (int t4 = 0; t4 < 4; ++t4) {          // K = 64 per stage, 16/mfma
            const int kc = 2 * t4 + half;
            bf16x8 af[2], bfr[4];
#pragma unroll
            for (int ms = 0; ms < 2; ++ms) {
                const int col = wm * 64 + ms * 32 + cl;
                af[ms] = pA[kc * 256 + swz(col)];
            }
#pragma unroll
            for (int ns = 0; ns < 4; ++ns) {
                const int col = wn * 128 + ns * 32 + cl;
                bfr[ns] = pB[kc * 256 + swz(col)];
            }
            __builtin_amdgcn_s_setprio(1);
#pragma unroll
            for (int ms = 0; ms < 2; ++ms)
#pragma unroll
                for (int ns = 0; ns < 4; ++ns)
                    acc[ms][ns] = __builtin_amdgcn_mfma_f32_32x32x16_bf16(
                        af[ms], bfr[ns], acc[ms][ns], 0, 0, 0);
            __builtin_amdgcn_s_setprio(0);
        }

        // ---- conv(st+1) after: vmcnt stall overlaps MFMA drain ----
        if (st + 1 < STAGES) {
            K12_CONV(fa, vA, smA[cur ^ 1], st + 1);
            if (st + 2 < STAGES) K12_LOAD(fa, st + 2, cAc);
            if (!diag) {
                K12_CONV(fb, vB, smB[cur ^ 1], st + 1);
                if (st + 2 < STAGES) K12_LOAD(fb, st + 2, cBc);
            }
        }
        asm volatile("s_waitcnt lgkmcnt(0)" ::: "memory");  // my ds ops done
        __builtin_amdgcn_s_barrier();   // writes(st+1) + reads(st) retired
    }
#undef K12_LOAD
#undef K12_CONV

    // row-quad packed bf16 stores: full-line coalesced, no atomics
    uint2* pt = parts + (size_t)(split * NTILE + t6) * 16384;
#pragma unroll
    for (int ms = 0; ms < 2; ++ms) {
        const int rowb = wm * 64 + ms * 32 + 4 * half;   // multiple of 4
#pragma unroll
        for (int ns = 0; ns < 4; ++ns) {
            const int colt = wn * 128 + ns * 32 + cl;
#pragma unroll
            for (int q = 0; q < 4; ++q) {                // rows rowb+8q .. +3
                uint2 w;
                w.x = f2bf(acc[ms][ns][q * 4 + 0]) | (f2bf(acc[ms][ns][q * 4 + 1]) << 16);
                w.y = f2bf(acc[ms][ns][q * 4 + 2]) | (f2bf(acc[ms][ns][q * 4 + 3]) << 16);
                pt[(size_t)(((rowb >> 2) + 2 * q) * 256 + colt)] = w;
            }
        }
    }
}

// ---------------------------------------------------------------------------
// kF: F (1024 x 680 fp32) -> Fb bf16 (1024 x 768, k-padded with zeros),
//     row-major. 768%8==0 and 680%8==0 -> clean uint4 (8 bf16) packing.
// ---------------------------------------------------------------------------
__global__ __launch_bounds__(256) void kf_conv(const float* __restrict__ F,
                                               uint4* __restrict__ Fb) {
    const int idx = blockIdx.x * 256 + threadIdx.x;   // 98304 uint4's
    const int row = idx / 96;                         // 768/8 = 96 per row
    const int c0  = (idx % 96) * 8;
    uint4 o = {0u, 0u, 0u, 0u};
    if (c0 < DIM) {
        const float4 a = *reinterpret_cast<const float4*>(F + (size_t)row * DIM + c0);
        const float4 b = *reinterpret_cast<const float4*>(F + (size_t)row * DIM + c0 + 4);
        o.x = f2bf(a.x) | (f2bf(a.y) << 16);
        o.y = f2bf(a.z) | (f2bf(a.w) << 16);
        o.z = f2bf(b.x) | (f2bf(b.y) << 16);
        o.w = f2bf(b.z) | (f2bf(b.w) << 16);
    }
    Fb[idx] = o;
}

// ---------------------------------------------------------------------------
// k2r: Mb[768x768 bf16] = sum over 36 split-partials per tile, + mirror.
//     Writes bf16 directly in k3's operand format (M symmetric ->
//     row-major Mb serves as both M and M^T).
// ---------------------------------------------------------------------------
__global__ __launch_bounds__(256) void k2_reduce(
        const uint2* __restrict__ parts, unsigned short* __restrict__ Mb) {
    const int t6 = blockIdx.y;
    const int tj = c_tj[t6];
    const int ti = c_ti[t6];
    const int idx4 = blockIdx.x * 256 + threadIdx.x;   // uint4 index, 8192/tile
    const int w0 = idx4 * 2;
    const int quad = w0 >> 8;
    const int c = w0 & 255;                            // even
    float s[8] = {0.f, 0.f, 0.f, 0.f, 0.f, 0.f, 0.f, 0.f};
    const uint4* base = reinterpret_cast<const uint4*>(parts) + idx4;
#pragma unroll 4
    for (int sp = 0; sp < SPLITS; ++sp) {
        const uint4 u = base[(size_t)(sp * NTILE + t6) * 8192];
        s[0] += bf2f((unsigned short)(u.x & 0xFFFF));
        s[1] += bf2f((unsigned short)(u.x >> 16));
        s[2] += bf2f((unsigned short)(u.y & 0xFFFF));
        s[3] += bf2f((unsigned short)(u.y >> 16));
        s[4] += bf2f((unsigned short)(u.z & 0xFFFF));
        s[5] += bf2f((unsigned short)(u.z >> 16));
        s[6] += bf2f((unsigned short)(u.w & 0xFFFF));
        s[7] += bf2f((unsigned short)(u.w >> 16));
    }
    const int R = tj * 256 + 4 * quad;
    const int C = ti * 256 + c;
#pragma unroll
    for (int i = 0; i < 4; ++i) {      // rows R..R+3, cols C,C+1
        const unsigned w = f2bf(s[i]) | (f2bf(s[4 + i]) << 16);
        *reinterpret_cast<unsigned*>(Mb + (size_t)(R + i) * DPAD + C) = w;
    }
    if (ti != tj) {                    // mirror: rows C,C+1, cols R..R+3
        uint2 m0, m1;
        m0.x = f2bf(s[0]) | (f2bf(s[1]) << 16);
        m0.y = f2bf(s[2]) | (f2bf(s[3]) << 16);
        m1.x = f2bf(s[4]) | (f2bf(s[5]) << 16);
        m1.y = f2bf(s[6]) | (f2bf(s[7]) << 16);
        *reinterpret_cast<uint2*>(Mb + (size_t)(C + 0) * DPAD + R) = m0;
        *reinterpret_cast<uint2*>(Mb + (size_t)(C + 1) * DPAD + R) = m1;
    }
}

// ---------------------------------------------------------------------------
// k3: out(1024 x 680) = F @ M via bf16 MFMA, full K=768. Operands Fb/Mb are
//     bf16 row-major with rows = contiguous K runs (M symmetric).
//     1 wave / block, 64x64 tile, grid (16, 11); operands L2/L3-resident.
//     global_load_lds with source-side XOR pre-swizzle, double-buffered
//     with counted vmcnt(16).
// ---------------------------------------------------------------------------
__global__ __launch_bounds__(64) void k3_mfma(const uint4* __restrict__ Fb,
                                              const uint4* __restrict__ Mb,
                                              float* __restrict__ out) {
    __shared__ uint4 sA[2][512];   // 64 cols x 8 k-chunks, swizzled, 2x8 KB
    __shared__ uint4 sB[2][512];
    const int t    = threadIdx.x;   // 0..63
    const int n0   = blockIdx.x * 64;
    const int i0   = blockIdx.y * 64;
    const int cl   = t & 31;
    const int half = t >> 5;

    f32x16 acc[2][2];
    const f32x16 zero = {};
    acc[0][0] = zero; acc[0][1] = zero; acc[1][0] = zero; acc[1][1] = zero;

#define K3_STAGE(ck_, buf_)                                                   \
    do {                                                                      \
        const int kcs_ = t & 7;                                               \
        _Pragma("unroll")                                                     \
        for (int j = 0; j < 8; ++j) {                                         \
            const int nl_ = j * 8 + (t >> 3);                                 \
            const int sc_ = (ck_) * 8 + (kcs_ ^ (nl_ & 7));                   \
            __builtin_amdgcn_global_load_lds(                                 \
                (glb_u32*)(Fb + (size_t)(n0 + nl_) * 96 + sc_),               \
                (lds_u32*)(&sA[(buf_)][j * 64 + t]), 16, 0, 0);               \
            __builtin_amdgcn_global_load_lds(                                 \
                (glb_u32*)(Mb + (size_t)(i0 + nl_) * 96 + sc_),               \
                (lds_u32*)(&sB[(buf_)][j * 64 + t]), 16, 0, 0);               \
        }                                                                     \
    } while (0)

    K3_STAGE(0, 0);
    asm volatile("s_waitcnt vmcnt(0)" ::: "memory");

    for (int ck = 0; ck < 12; ++ck) {          // K = 768 = 12 x 64
        const int cur = ck & 1;
        if (ck + 1 < 12) {
            asm volatile("s_waitcnt lgkmcnt(0)" ::: "memory");
            K3_STAGE(ck + 1, cur ^ 1);
            asm volatile("s_waitcnt vmcnt(16)" ::: "memory");  // cur's 16 done
        }
        const bf16x8* pA = reinterpret_cast<const bf16x8*>(sA[cur]);
        const bf16x8* pB = reinterpret_cast<const bf16x8*>(sB[cur]);
#pragma unroll
        for (int t4 = 0; t4 < 4; ++t4) {
            const int kc = 2 * t4 + half;
            bf16x8 af[2], bv[2];
#pragma unroll
            for (int ms = 0; ms < 2; ++ms) {
                const int col = ms * 32 + cl;
                af[ms] = pA[col * 8 + (kc ^ (col & 7))];
            }
#pragma unroll
            for (int ns = 0; ns < 2; ++ns) {
                const int col = ns * 32 + cl;
                bv[ns] = pB[col * 8 + (kc ^ (col & 7))];
            }
#pragma unroll
            for (int ms = 0; ms < 2; ++ms)
#pragma unroll
                for (int ns = 0; ns < 2; ++ns)
                    acc[ms][ns] = __builtin_amdgcn_mfma_f32_32x32x16_bf16(
                        af[ms], bv[ns], acc[ms][ns], 0, 0, 0);
        }
    }
#undef K3_STAGE

    // C layout (32x32): col = lane&31, row = (reg&3) + 8*(reg>>2) + 4*half
#pragma unroll
    for (int ms = 0; ms < 2; ++ms) {
        const int rowb = ms * 32 + 4 * half;
#pragma unroll
        for (int ns = 0; ns < 2; ++ns) {
            const int col = i0 + ns * 32 + cl;
            if (col < DIM) {
#pragma unroll
                for (int q = 0; q < 4; ++q)
#pragma unroll
                    for (int j = 0; j < 4; ++j)
                        out[(size_t)(n0 + rowb + 8 * q + j) * DIM + col]
                            = acc[ms][ns][4 * q + j];
            }
        }
    }
}

extern "C" void kernel_launch(void* const* d_in, const int* in_sizes, int n_in,
                              void* d_out, int out_size, void* d_ws, size_t ws_size,
                              hipStream_t stream) {
    const float* F  = (const float*)d_in[0];   // (1024, 680)
    const float* D  = (const float*)d_in[1];   // (48, 24, 48, 680)
    const float* qw = (const float*)d_in[2];   // (24,)
    float* out = (float*)d_out;
    char*  ws  = (char*)d_ws;

    uint2* parts = (uint2*)ws;                                  // 27.0 MiB bf16
    const size_t parts_bytes = (size_t)SPLITS * NTILE * 16384 * 8;  // 28,311,552
    unsigned short* Mb = (unsigned short*)(ws + parts_bytes);   // 1.125 MiB
    const size_t mb_bytes = (size_t)DPAD * DPAD * 2;            // 1,179,648
    uint4* Fb = (uint4*)(ws + parts_bytes + mb_bytes);          // 1.5 MiB

    k12_gram<<<dim3(SPLITS * NTILE), 512, 0, stream>>>(D, qw, parts);
    kf_conv<<<dim3(1024 * DPAD / 8 / 256), 256, 0, stream>>>(F, Fb);
    k2_reduce<<<dim3(32, NTILE), 256, 0, stream>>>(parts, Mb);
    k3_mfma<<<dim3(16, 11), 64, 0, stream>>>(Fb, (const uint4*)Mb, out);
}

// Round 10
// 254.812 us; speedup vs baseline: 5.4062x; 1.0012x over previous
//
#include <hip/hip_runtime.h>
#include <stdint.h>

#define DIM    680
#define DPAD   768      // 3 x 256 tiles
#define NB_Q   24
#define SPLITS 36
#define STAGES 24       // 864 g-chunks / SPLITS
#define NTILE  6        // upper-triangle 256x256 tiles of 3x3

typedef __bf16 bf16x8 __attribute__((ext_vector_type(8)));
typedef __bf16 bf16x2 __attribute__((ext_vector_type(2)));
typedef float  f32x16 __attribute__((ext_vector_type(16)));
typedef float  f32x4  __attribute__((ext_vector_type(4)));

typedef __attribute__((address_space(3))) unsigned       lds_u32;
typedef __attribute__((address_space(1))) const unsigned glb_u32;

__constant__ int c_tj[NTILE] = {0, 0, 0, 1, 1, 2};
__constant__ int c_ti[NTILE] = {0, 1, 2, 1, 2, 2};

static __device__ __forceinline__ unsigned f2bf(float x) {
    union { float f; unsigned u; } c; c.f = x;
    unsigned u = c.u;
    return (u + 0x7FFFu + ((u >> 16) & 1u)) >> 16;  // RNE
}

// HW packed convert: compiler emits v_cvt_pk_bf16_f32 (RNE) for paired casts.
static __device__ __forceinline__ unsigned pk2(float lo, float hi) {
    bf16x2 v = {(__bf16)lo, (__bf16)hi};
    return __builtin_bit_cast(unsigned, v);
}

static __device__ __forceinline__ float bf2f(unsigned short h) {
    union { unsigned u; float f; } c; c.u = ((unsigned)h) << 16;
    return c.f;
}

// LDS bank swizzle for the [kc][col] tile: spreads conv's stride-64B lane
// writes across all 8 bank-groups; bijective within each aligned 8-col block
// so frag reads (contiguous 32-col spans) stay conflict-free.
static __device__ __forceinline__ int swz(int col) {
    return col ^ ((col >> 2) & 7);
}

// ---------------------------------------------------------------------------
// k12-v6 (fused k1+k2): parts[split][tile] = sum over the split's 24 chunks
//     of A_band(tj)^T * A_band(ti), A = D * sqrt(qw[beta(g)]) in bf16,
//     computed on the fly from fp32 D.
//
//     v6 vs v5 (R9: total 255, k12 below the 88us fill cutoff -> blind):
//     conv quarters INTERLEAVED into the t4 MFMA loop.  v5 ran MFMA(st)
//     then conv(st+1) as two macro-blocks; with 8 barrier-locked waves in
//     identical program order, both waves of a SIMD saturate the MFMA pipe
//     together then the VALU pipe together -- each pipe idle half the
//     stage.  Interleaving {frag reads, 8 MFMA, conv quarter} per t4 puts
//     VALU ops adjacent to MFMA issue so the two pipes dual-issue within a
//     wave (separate pipes, m114).  Scale vector computed once per stage
//     (identical for both bands -- was computed twice).  Stage-st+2 loads
//     issued at stage end, flying across the barrier into the next stage.
// ---------------------------------------------------------------------------
__global__ __launch_bounds__(512) void k12_gram(
        const float* __restrict__ D, const float* __restrict__ qw,
        uint2* __restrict__ parts) {
    __shared__ float sq[NB_Q];
    __shared__ uint4 smA[2][2048];   // [kc][col] kc-major, swizzled, 2 x 32 KB
    __shared__ uint4 smB[2][2048];
    const int t  = threadIdx.x;
    const int h       = blockIdx.x;              // 0..215
    const int logical = (h & 7) * 27 + (h >> 3); // bijective (216 = 8*27)
    const int split   = logical / 6;
    const int t6      = logical % 6;
    const int tj    = c_tj[t6];   // row band of M
    const int ti    = c_ti[t6];   // col band of M
    const bool diag = (tj == ti);
    // staging: thread owns rows rg*8..+7 (= k-chunk kc=rg) x cols c0..c0+3
    const int rg = t >> 6;        // 0..7, wave-uniform
    const int c0 = 4 * (t & 63);  // 0..252; lane-contiguous float4 => coalesced
    const int cA = tj * 256 + c0;
    const int cB = ti * 256 + c0;
    const bool vA = (cA < DIM);   // 680%4==0: whole float4 valid or not
    const bool vB = (cB < DIM);
    const int cAc = vA ? cA : (DIM - 4);   // clamp: uniform VMEM counts
    const int cBc = vB ? cB : (DIM - 4);
    // MFMA mapping
    const int wave  = t >> 6;
    const int lane  = t & 63;
    const int wm    = wave & 3;   // m: 64-row band
    const int wn    = wave >> 2;  // n: 128-col band
    const int cl    = lane & 31;
    const int half  = lane >> 5;

    f32x16 acc[2][4];
    const f32x16 zero = {};
#pragma unroll
    for (int a = 0; a < 2; ++a)
#pragma unroll
        for (int b = 0; b < 4; ++b) acc[a][b] = zero;

    f32x4 fa[8], fb[8];   // staged rows (static indexing only)

#define K12_LOAD(reg_, st_, csrc_)                                            \
    do {                                                                      \
        const int g0_ = (split * STAGES + (st_)) * 64 + rg * 8;               \
        _Pragma("unroll")                                                     \
        for (int j_ = 0; j_ < 8; ++j_)                                        \
            reg_[j_] = *reinterpret_cast<const f32x4*>(                       \
                D + (size_t)(g0_ + j_) * DIM + (csrc_));                      \
    } while (0)

// full-stage conv (prologue only)
#define K12_CONV(reg_, valid_, smx_, st_)                                     \
    do {                                                                      \
        const int G_ = (split * STAGES + (st_)) * 64 + rg * 8;                \
        const int q_ = G_ / 48;                                               \
        const int r_ = G_ - q_ * 48;                                          \
        const float s0_ = sq[q_ % 24];                                        \
        const float s1_ = sq[(q_ + 1) % 24];                                  \
        float sc_[8];                                                         \
        _Pragma("unroll")                                                     \
        for (int j_ = 0; j_ < 8; ++j_) sc_[j_] = (r_ + j_ < 48) ? s0_ : s1_;  \
        _Pragma("unroll")                                                     \
        for (int jc_ = 0; jc_ < 4; ++jc_) {                                   \
            float e_[8];                                                      \
            _Pragma("unroll")                                                 \
            for (int j_ = 0; j_ < 8; ++j_)                                    \
                e_[j_] = (valid_) ? reg_[j_][jc_] * sc_[j_] : 0.f;            \
            uint4 o_;                                                         \
            o_.x = pk2(e_[0], e_[1]);                                         \
            o_.y = pk2(e_[2], e_[3]);                                         \
            o_.z = pk2(e_[4], e_[5]);                                         \
            o_.w = pk2(e_[6], e_[7]);                                         \
            smx_[rg * 256 + swz(c0 + jc_)] = o_;                              \
        }                                                                     \
    } while (0)

// one column-quarter of conv: 8 mul + 4 cvt_pk + 1 ds_write per band
#define K12_CONVQ(reg_, valid_, smx_, jc_)                                    \
    do {                                                                      \
        float e_[8];                                                          \
        _Pragma("unroll")                                                     \
        for (int j_ = 0; j_ < 8; ++j_)                                        \
            e_[j_] = (valid_) ? reg_[j_][jc_] * scv[j_] : 0.f;                \
        uint4 o_;                                                             \
        o_.x = pk2(e_[0], e_[1]);                                             \
        o_.y = pk2(e_[2], e_[3]);                                             \
        o_.z = pk2(e_[4], e_[5]);                                             \
        o_.w = pk2(e_[6], e_[7]);                                             \
        smx_[rg * 256 + swz(c0 + (jc_))] = o_;                                \
    } while (0)

    // prologue: stage-0 loads fly while sq is set up
    K12_LOAD(fa, 0, cAc);
    if (!diag) K12_LOAD(fb, 0, cBc);
    if (t < NB_Q) sq[t] = sqrtf(qw[t]);
    asm volatile("s_waitcnt lgkmcnt(0)" ::: "memory");
    __builtin_amdgcn_s_barrier();   // sq visible (vmcnt untouched)
    K12_CONV(fa, vA, smA[0], 0);    // auto-vmcnt waits on fa here
    if (!diag) K12_CONV(fb, vB, smB[0], 0);
    K12_LOAD(fa, 1, cAc);           // st1 loads fly across barrier + stage 0
    if (!diag) K12_LOAD(fb, 1, cBc);
    asm volatile("s_waitcnt lgkmcnt(0)" ::: "memory");
    __builtin_amdgcn_s_barrier();   // buf0 complete for all waves

    for (int st = 0; st < STAGES; ++st) {
        const int cur = st & 1;
        const bool pre = (st + 1 < STAGES);

        // per-stage scale vector for conv(st+1) -- same for both bands
        float scv[8];
        {
            const int G_ = (split * STAGES + (st + 1)) * 64 + rg * 8;
            const int q_ = G_ / 48;
            const int r_ = G_ - q_ * 48;
            const float s0_ = sq[q_ % 24];
            const float s1_ = sq[(q_ + 1) % 24];
#pragma unroll
            for (int j_ = 0; j_ < 8; ++j_) scv[j_] = (r_ + j_ < 48) ? s0_ : s1_;
        }

        const bf16x8* pA = reinterpret_cast<const bf16x8*>(smA[cur]);
        const bf16x8* pB = diag ? pA : reinterpret_cast<const bf16x8*>(smB[cur]);
        uint4* wA = &smA[cur ^ 1][0];
        uint4* wB = &smB[cur ^ 1][0];
#pragma unroll
        for (int t4 = 0; t4 < 4; ++t4) {          // K = 64 per stage, 16/mfma
            const int kc = 2 * t4 + half;
            bf16x8 af[2], bfr[4];
#pragma unroll
            for (int ms = 0; ms < 2; ++ms) {
                const int col = wm * 64 + ms * 32 + cl;
                af[ms] = pA[kc * 256 + swz(col)];
            }
#pragma unroll
            for (int ns = 0; ns < 4; ++ns) {
                const int col = wn * 128 + ns * 32 + cl;
                bfr[ns] = pB[kc * 256 + swz(col)];
            }
            __builtin_amdgcn_s_setprio(1);
#pragma unroll
            for (int ms = 0; ms < 2; ++ms)
#pragma unroll
                for (int ns = 0; ns < 4; ++ns)
                    acc[ms][ns] = __builtin_amdgcn_mfma_f32_32x32x16_bf16(
                        af[ms], bfr[ns], acc[ms][ns], 0, 0, 0);
            __builtin_amdgcn_s_setprio(0);
            // conv quarter t4 of stage st+1: VALU dual-issues under the
            // MFMA drain; writes go to the opposite buffer.
            if (pre) {
                K12_CONVQ(fa, vA, wA, t4);
                if (!diag) K12_CONVQ(fb, vB, wB, t4);
            }
        }

        if (st + 2 < STAGES) {
            K12_LOAD(fa, st + 2, cAc);
            if (!diag) K12_LOAD(fb, st + 2, cBc);
        }
        asm volatile("s_waitcnt lgkmcnt(0)" ::: "memory");  // my ds ops done
        __builtin_amdgcn_s_barrier();   // writes(st+1) + reads(st) retired
    }
#undef K12_LOAD
#undef K12_CONV
#undef K12_CONVQ

    // row-quad packed bf16 stores: full-line coalesced, no atomics
    uint2* pt = parts + (size_t)(split * NTILE + t6) * 16384;
#pragma unroll
    for (int ms = 0; ms < 2; ++ms) {
        const int rowb = wm * 64 + ms * 32 + 4 * half;   // multiple of 4
#pragma unroll
        for (int ns = 0; ns < 4; ++ns) {
            const int colt = wn * 128 + ns * 32 + cl;
#pragma unroll
            for (int q = 0; q < 4; ++q) {                // rows rowb+8q .. +3
                uint2 w;
                w.x = f2bf(acc[ms][ns][q * 4 + 0]) | (f2bf(acc[ms][ns][q * 4 + 1]) << 16);
                w.y = f2bf(acc[ms][ns][q * 4 + 2]) | (f2bf(acc[ms][ns][q * 4 + 3]) << 16);
                pt[(size_t)(((rowb >> 2) + 2 * q) * 256 + colt)] = w;
            }
        }
    }
}

// ---------------------------------------------------------------------------
// k_prep (merged kf_conv + k2_reduce): one launch instead of two.
//   blocks 0..191   : k2r -- Mb[768x768 bf16] = sum of 36 split-partials per
//                     tile, + mirror (M symmetric; row-major Mb = M = M^T).
//   blocks 192..575 : kf  -- F (1024x680 fp32) -> Fb bf16 (1024x768 padded).
// ---------------------------------------------------------------------------
__global__ __launch_bounds__(256) void k_prep(
        const uint2* __restrict__ parts, unsigned short* __restrict__ Mb,
        const float* __restrict__ F, uint4* __restrict__ Fb) {
    const int b = blockIdx.x;
    if (b < 192) {
        const int t6 = b >> 5;
        const int tj = c_tj[t6];
        const int ti = c_ti[t6];
        const int idx4 = (b & 31) * 256 + threadIdx.x;   // uint4 idx, 8192/tile
        const int w0 = idx4 * 2;
        const int quad = w0 >> 8;
        const int c = w0 & 255;                          // even
        float s[8] = {0.f, 0.f, 0.f, 0.f, 0.f, 0.f, 0.f, 0.f};
        const uint4* base = reinterpret_cast<const uint4*>(parts) + idx4;
#pragma unroll 4
        for (int sp = 0; sp < SPLITS; ++sp) {
            const uint4 u = base[(size_t)(sp * NTILE + t6) * 8192];
            s[0] += bf2f((unsigned short)(u.x & 0xFFFF));
            s[1] += bf2f((unsigned short)(u.x >> 16));
            s[2] += bf2f((unsigned short)(u.y & 0xFFFF));
            s[3] += bf2f((unsigned short)(u.y >> 16));
            s[4] += bf2f((unsigned short)(u.z & 0xFFFF));
            s[5] += bf2f((unsigned short)(u.z >> 16));
            s[6] += bf2f((unsigned short)(u.w & 0xFFFF));
            s[7] += bf2f((unsigned short)(u.w >> 16));
        }
        const int R = tj * 256 + 4 * quad;
        const int C = ti * 256 + c;
#pragma unroll
        for (int i = 0; i < 4; ++i) {      // rows R..R+3, cols C,C+1
            const unsigned w = f2bf(s[i]) | (f2bf(s[4 + i]) << 16);
            *reinterpret_cast<unsigned*>(Mb + (size_t)(R + i) * DPAD + C) = w;
        }
        if (ti != tj) {                    // mirror: rows C,C+1, cols R..R+3
            uint2 m0, m1;
            m0.x = f2bf(s[0]) | (f2bf(s[1]) << 16);
            m0.y = f2bf(s[2]) | (f2bf(s[3]) << 16);
            m1.x = f2bf(s[4]) | (f2bf(s[5]) << 16);
            m1.y = f2bf(s[6]) | (f2bf(s[7]) << 16);
            *reinterpret_cast<uint2*>(Mb + (size_t)(C + 0) * DPAD + R) = m0;
            *reinterpret_cast<uint2*>(Mb + (size_t)(C + 1) * DPAD + R) = m1;
        }
    } else {
        const int idx = (b - 192) * 256 + threadIdx.x;   // 98304 uint4's
        const int row = idx / 96;                        // 768/8 = 96 per row
        const int c0  = (idx % 96) * 8;
        uint4 o = {0u, 0u, 0u, 0u};
        if (c0 < DIM) {
            const float4 a = *reinterpret_cast<const float4*>(F + (size_t)row * DIM + c0);
            const float4 bb = *reinterpret_cast<const float4*>(F + (size_t)row * DIM + c0 + 4);
            o.x = f2bf(a.x) | (f2bf(a.y) << 16);
            o.y = f2bf(a.z) | (f2bf(a.w) << 16);
            o.z = f2bf(bb.x) | (f2bf(bb.y) << 16);
            o.w = f2bf(bb.z) | (f2bf(bb.w) << 16);
        }
        Fb[idx] = o;
    }
}

// ---------------------------------------------------------------------------
// k3: out(1024 x 680) = F @ M via bf16 MFMA, full K=768. Operands Fb/Mb are
//     bf16 row-major with rows = contiguous K runs (M symmetric).
//     1 wave / block, 64x64 tile, grid (16, 11); operands L2/L3-resident.
//     global_load_lds with source-side XOR pre-swizzle, double-buffered
//     with counted vmcnt(16).
// ---------------------------------------------------------------------------
__global__ __launch_bounds__(64) void k3_mfma(const uint4* __restrict__ Fb,
                                              const uint4* __restrict__ Mb,
                                              float* __restrict__ out) {
    __shared__ uint4 sA[2][512];   // 64 cols x 8 k-chunks, swizzled, 2x8 KB
    __shared__ uint4 sB[2][512];
    const int t    = threadIdx.x;   // 0..63
    const int n0   = blockIdx.x * 64;
    const int i0   = blockIdx.y * 64;
    const int cl   = t & 31;
    const int half = t >> 5;

    f32x16 acc[2][2];
    const f32x16 zero = {};
    acc[0][0] = zero; acc[0][1] = zero; acc[1][0] = zero; acc[1][1] = zero;

#define K3_STAGE(ck_, buf_)                                                   \
    do {                                                                      \
        const int kcs_ = t & 7;                                               \
        _Pragma("unroll")                                                     \
        for (int j = 0; j < 8; ++j) {                                         \
            const int nl_ = j * 8 + (t >> 3);                                 \
            const int sc_ = (ck_) * 8 + (kcs_ ^ (nl_ & 7));                   \
            __builtin_amdgcn_global_load_lds(                                 \
                (glb_u32*)(Fb + (size_t)(n0 + nl_) * 96 + sc_),               \
                (lds_u32*)(&sA[(buf_)][j * 64 + t]), 16, 0, 0);               \
            __builtin_amdgcn_global_load_lds(                                 \
                (glb_u32*)(Mb + (size_t)(i0 + nl_) * 96 + sc_),               \
                (lds_u32*)(&sB[(buf_)][j * 64 + t]), 16, 0, 0);               \
        }                                                                     \
    } while (0)

    K3_STAGE(0, 0);
    asm volatile("s_waitcnt vmcnt(0)" ::: "memory");

    for (int ck = 0; ck < 12; ++ck) {          // K = 768 = 12 x 64
        const int cur = ck & 1;
        if (ck + 1 < 12) {
            asm volatile("s_waitcnt lgkmcnt(0)" ::: "memory");
            K3_STAGE(ck + 1, cur ^ 1);
            asm volatile("s_waitcnt vmcnt(16)" ::: "memory");  // cur's 16 done
        }
        const bf16x8* pA = reinterpret_cast<const bf16x8*>(sA[cur]);
        const bf16x8* pB = reinterpret_cast<const bf16x8*>(sB[cur]);
#pragma unroll
        for (int t4 = 0; t4 < 4; ++t4) {
            const int kc = 2 * t4 + half;
            bf16x8 af[2], bv[2];
#pragma unroll
            for (int ms = 0; ms < 2; ++ms) {
                const int col = ms * 32 + cl;
                af[ms] = pA[col * 8 + (kc ^ (col & 7))];
            }
#pragma unroll
            for (int ns = 0; ns < 2; ++ns) {
                const int col = ns * 32 + cl;
                bv[ns] = pB[col * 8 + (kc ^ (col & 7))];
            }
#pragma unroll
            for (int ms = 0; ms < 2; ++ms)
#pragma unroll
                for (int ns = 0; ns < 2; ++ns)
                    acc[ms][ns] = __builtin_amdgcn_mfma_f32_32x32x16_bf16(
                        af[ms], bv[ns], acc[ms][ns], 0, 0, 0);
        }
    }
#undef K3_STAGE

    // C layout (32x32): col = lane&31, row = (reg&3) + 8*(reg>>2) + 4*half
#pragma unroll
    for (int ms = 0; ms < 2; ++ms) {
        const int rowb = ms * 32 + 4 * half;
#pragma unroll
        for (int ns = 0; ns < 2; ++ns) {
            const int col = i0 + ns * 32 + cl;
            if (col < DIM) {
#pragma unroll
                for (int q = 0; q < 4; ++q)
#pragma unroll
                    for (int j = 0; j < 4; ++j)
                        out[(size_t)(n0 + rowb + 8 * q + j) * DIM + col]
                            = acc[ms][ns][4 * q + j];
            }
        }
    }
}

extern "C" void kernel_launch(void* const* d_in, const int* in_sizes, int n_in,
                              void* d_out, int out_size, void* d_ws, size_t ws_size,
                              hipStream_t stream) {
    const float* F  = (const float*)d_in[0];   // (1024, 680)
    const float* D  = (const float*)d_in[1];   // (48, 24, 48, 680)
    const float* qw = (const float*)d_in[2];   // (24,)
    float* out = (float*)d_out;
    char*  ws  = (char*)d_ws;

    uint2* parts = (uint2*)ws;                                  // 27.0 MiB bf16
    const size_t parts_bytes = (size_t)SPLITS * NTILE * 16384 * 8;  // 28,311,552
    unsigned short* Mb = (unsigned short*)(ws + parts_bytes);   // 1.125 MiB
    const size_t mb_bytes = (size_t)DPAD * DPAD * 2;            // 1,179,648
    uint4* Fb = (uint4*)(ws + parts_bytes + mb_bytes);          // 1.5 MiB

    k12_gram<<<dim3(SPLITS * NTILE), 512, 0, stream>>>(D, qw, parts);
    k_prep<<<dim3(576), 256, 0, stream>>>(parts, Mb, F, Fb);
    k3_mfma<<<dim3(16, 11), 64, 0, stream>>>(Fb, (const uint4*)Mb, out);
}